// Round 2
// baseline (1576.382 us; speedup 1.0000x reference)
//
#include <hip/hip_runtime.h>
#include <hip/hip_bf16.h>
#include <math.h>

#define Bc   32
#define Hc   56
#define Wcc  56
#define Nc   3136
#define C0c  128
#define Cpc  32
#define Cac  96
#define HDc  12
#define EPSc 1e-5f
#define SCALEc 0.28867513459481287f   /* 1/sqrt(12) */

__device__ __forceinline__ float gelu_f(float x) {
    return 0.5f * x * (1.0f + erff(x * 0.7071067811865475f));
}

// ---------------- LN1: (B,N,128) -> xa (B,N,96) fp32 + xc_img (B,32,56,56) fp32
__global__ __launch_bounds__(256) void ln1_kernel(const float* __restrict__ x,
        const float* __restrict__ g, const float* __restrict__ be,
        float* __restrict__ xa, float* __restrict__ xc_img)
{
    int wv = threadIdx.x >> 6, lane = threadIdx.x & 63;
    int row = blockIdx.x * 4 + wv;
    if (row >= Bc * Nc) return;
    const float* xr = x + (size_t)row * 128;
    float x0 = xr[lane];
    float x1 = xr[lane + 64];
    float s = x0 + x1, q = x0 * x0 + x1 * x1;
    for (int o = 32; o; o >>= 1) { s += __shfl_xor(s, o); q += __shfl_xor(q, o); }
    float mean = s * (1.f / 128.f);
    float inv = rsqrtf(q * (1.f / 128.f) - mean * mean + EPSc);
    int b = row / Nc, n = row % Nc;
    {
        int c = lane;
        float y = (x0 - mean) * inv * g[c] + be[c];
        if (c < Cpc) xc_img[(size_t)(b * Cpc + c) * Nc + n] = y;
        else         xa[(size_t)row * Cac + (c - Cpc)] = y;
    }
    {
        int c = lane + 64;
        float y = (x1 - mean) * inv * g[c] + be[c];
        xa[(size_t)row * Cac + (c - Cpc)] = y;
    }
}

// ---------------- Haar DWT: src (B,32,h,w) [channel stride cs] -> sub (B,128,h2,w2), zero-pad
__global__ void dwt_kernel(const float* __restrict__ src, int cs, int h, int w,
                           int h2, int w2, float* __restrict__ sub)
{
    int t = blockIdx.x * blockDim.x + threadIdx.x;
    int total = Bc * 32 * h2 * w2;
    if (t >= total) return;
    int xx = t % w2; int r = t / w2;
    int yy = r % h2; r /= h2;
    int c = r & 31; int b = r >> 5;
    const float* sp = src + (size_t)cs * (b * 32 + c) * h * w;
    int y0 = yy * 2, x0 = xx * 2;
    bool xe = (x0 + 1 < w), ye = (y0 + 1 < h);
    float a  = sp[y0 * w + x0];
    float bb = xe ? sp[y0 * w + x0 + 1] : 0.f;
    float cc = ye ? sp[(y0 + 1) * w + x0] : 0.f;
    float dd = (xe && ye) ? sp[(y0 + 1) * w + x0 + 1] : 0.f;
    size_t pl = (size_t)h2 * w2;
    size_t ob = (size_t)(b * 128 + c * 4) * pl + yy * w2 + xx;
    sub[ob]          = ( a + bb + cc + dd) * 0.5f;
    sub[ob + pl]     = (-a - bb + cc + dd) * 0.5f;
    sub[ob + 2 * pl] = (-a + bb - cc + dd) * 0.5f;
    sub[ob + 3 * pl] = ( a - bb - cc + dd) * 0.5f;
}

// ---------------- depthwise 3x3 SAME, +bias? then *scale, +addbuf?
__global__ void dw3x3_kernel(const float* __restrict__ src, const float* __restrict__ wt,
        const float* __restrict__ scale, const float* __restrict__ bias,
        const float* __restrict__ addb, float* __restrict__ dst,
        int C, int h, int w)
{
    int t = blockIdx.x * blockDim.x + threadIdx.x;
    int total = Bc * C * h * w;
    if (t >= total) return;
    int x = t % w; int r = t / w;
    int y = r % h; r /= h;
    int c = r % C;
    const float* sp = src + (size_t)(t - x - y * w);
    float acc = 0.f;
    #pragma unroll
    for (int u = 0; u < 3; u++) {
        int yy = y + u - 1;
        if (yy < 0 || yy >= h) continue;
        #pragma unroll
        for (int v = 0; v < 3; v++) {
            int xx = x + v - 1;
            if (xx < 0 || xx >= w) continue;
            acc += sp[yy * w + xx] * wt[(u * 3 + v) * C + c];
        }
    }
    if (bias) acc += bias[c];
    acc *= scale[c];
    if (addb) acc += addb[t];
    dst[t] = acc;
}

// ---------------- Haar IDWT (+ll add, crop): tlvl (B,128,h2,w2), nxt (B,32,h2,w2)? -> out (B,32,ho,wo)
__global__ void idwt_kernel(const float* __restrict__ tl, const float* __restrict__ nxt,
        float* __restrict__ outp, int h2, int w2, int ho, int wo)
{
    int t = blockIdx.x * blockDim.x + threadIdx.x;
    int total = Bc * 32 * ho * wo;
    if (t >= total) return;
    int x = t % wo; int r = t / wo;
    int y = r % ho; r /= ho;
    int c = r & 31; int b = r >> 5;
    int y2 = y >> 1, x2 = x >> 1;
    size_t pl = (size_t)h2 * w2;
    size_t base = (size_t)(b * 128 + c * 4) * pl + y2 * w2 + x2;
    float ll = tl[base];
    if (nxt) ll += nxt[(size_t)(b * 32 + c) * pl + y2 * w2 + x2];
    float lh = tl[base + pl], hl = tl[base + 2 * pl], hh = tl[base + 3 * pl];
    float v;
    if ((y & 1) == 0) v = ((x & 1) == 0) ? (ll - lh - hl + hh) : (ll - lh + hl - hh);
    else              v = ((x & 1) == 0) ? (ll + lh - hl - hh) : (ll + lh + hl + hh);
    outp[t] = v * 0.5f;
}

// ---------------- cp2d: full 3x3 conv 32->32 SAME on (B,32,56,56), weight HWIO (3,3,32,32)
__global__ void cp2d_kernel(const float* __restrict__ src, const float* __restrict__ wt,
        const float* __restrict__ bias, float* __restrict__ dst)
{
    int t = blockIdx.x * blockDim.x + threadIdx.x;
    int total = Bc * 32 * Nc;
    if (t >= total) return;
    int x = t % Wcc; int r = t / Wcc;
    int y = r % Hc; r /= Hc;
    int co = r & 31; int b = r >> 5;
    const float* sp0 = src + (size_t)b * 32 * Nc;
    float acc = bias[co];
    #pragma unroll
    for (int u = 0; u < 3; u++) {
        int yy = y + u - 1;
        if (yy < 0 || yy >= Hc) continue;
        #pragma unroll
        for (int v = 0; v < 3; v++) {
            int xx = x + v - 1;
            if (xx < 0 || xx >= Wcc) continue;
            const float* sp = sp0 + yy * Wcc + xx;
            const float* wp = wt + ((u * 3 + v) * 32) * 32 + co;
            #pragma unroll
            for (int ci = 0; ci < 32; ci++)
                acc += sp[(size_t)ci * Nc] * wp[ci * 32];
        }
    }
    dst[t] = acc;
}

// ---------------- cn: LN over 32 ch (strided gather) + gelu -> attn_cat cols 96..127
__global__ void cn_kernel(const float* __restrict__ cb, const float* __restrict__ g,
        const float* __restrict__ be, float* __restrict__ attn_cat)
{
    int t = blockIdx.x * blockDim.x + threadIdx.x;
    if (t >= Bc * Nc) return;
    int b = t / Nc, n = t % Nc;
    const float* p = cb + (size_t)b * 32 * Nc + n;
    float v[32]; float s = 0.f;
    #pragma unroll
    for (int c = 0; c < 32; c++) { v[c] = p[(size_t)c * Nc]; s += v[c]; }
    float mean = s * (1.f / 32.f), q = 0.f;
    #pragma unroll
    for (int c = 0; c < 32; c++) { float d = v[c] - mean; q += d * d; }
    float inv = rsqrtf(q * (1.f / 32.f) + EPSc);
    float* o = attn_cat + (size_t)t * 128 + 96;
    #pragma unroll
    for (int c = 0; c < 32; c++)
        o[c] = gelu_f((v[c] - mean) * inv * g[c] + be[c]);
}

// ---------------- sr: depthwise ks x ks stride ks VALID, reading xa (B,N,96); out (B,L,96)
__global__ void sr_kernel(const float* __restrict__ xa, const float* __restrict__ wt,
        const float* __restrict__ bias, float* __restrict__ outp, int ks, int Ld)
{
    int t = blockIdx.x * blockDim.x + threadIdx.x;
    int total = Bc * Ld * Ld * Cac;
    if (t >= total) return;
    int c = t % Cac; int r = t / Cac;
    int j = r % Ld; r /= Ld;
    int i = r % Ld; int b = r / Ld;
    float acc = bias[c];
    for (int u = 0; u < ks; u++)
        for (int v = 0; v < ks; v++)
            acc += xa[(size_t)(b * Nc + (i * ks + u) * Wcc + (j * ks + v)) * Cac + c]
                 * wt[(u * ks + v) * Cac + c];
    outp[t] = acc;
}

// ---------------- LN over 96 + gelu, wave-per-row
__global__ __launch_bounds__(256) void ln96_kernel(const float* __restrict__ src,
        const float* __restrict__ g, const float* __restrict__ be,
        float* __restrict__ dst, int R)
{
    int wv = threadIdx.x >> 6, lane = threadIdx.x & 63;
    int row = blockIdx.x * 4 + wv;
    if (row >= R) return;
    const float* sp = src + (size_t)row * 96;
    float x0 = sp[lane];
    float x1 = (lane < 32) ? sp[64 + lane] : 0.f;
    float s = x0 + x1, q = x0 * x0 + x1 * x1;
    for (int o = 32; o; o >>= 1) { s += __shfl_xor(s, o); q += __shfl_xor(q, o); }
    float mean = s * (1.f / 96.f);
    float inv = rsqrtf(q * (1.f / 96.f) - mean * mean + EPSc);
    dst[(size_t)row * 96 + lane] = gelu_f((x0 - mean) * inv * g[lane] + be[lane]);
    if (lane < 32)
        dst[(size_t)row * 96 + 64 + lane] =
            gelu_f((x1 - mean) * inv * g[64 + lane] + be[64 + lane]);
}

// ---------------- generic tiled matmul: C(MxN) = A(MxK fp32) x W(KxN fp32) [+bias][+res]
__global__ __launch_bounds__(256) void matmul_kernel(const float* __restrict__ A,
        const float* __restrict__ W, const float* __restrict__ bias,
        const float* __restrict__ res, float* __restrict__ Cto,
        int M, int N, int K)
{
    __shared__ float As[16][64];
    __shared__ float Ws[16][68];
    int tid = threadIdx.x;
    int m0 = blockIdx.y * 64, n0 = blockIdx.x * 64;
    float acc[4][4] = {{0.f}};
    int tm = (tid >> 4) << 2, tn = (tid & 15) << 2;
    int aR = tid >> 2, aC = (tid & 3) << 2;
    int wR = tid >> 4, wC = (tid & 15) << 2;
    for (int k0 = 0; k0 < K; k0 += 16) {
        float4 av = make_float4(0.f, 0.f, 0.f, 0.f);
        if (m0 + aR < M) av = *(const float4*)(A + (size_t)(m0 + aR) * K + k0 + aC);
        As[aC][aR] = av.x; As[aC + 1][aR] = av.y; As[aC + 2][aR] = av.z; As[aC + 3][aR] = av.w;
        const float* wp = W + (size_t)(k0 + wR) * N + n0 + wC;
        #pragma unroll
        for (int j = 0; j < 4; j++)
            Ws[wR][wC + j] = (n0 + wC + j < N) ? wp[j] : 0.f;
        __syncthreads();
        #pragma unroll
        for (int k = 0; k < 16; k++) {
            float a0 = As[k][tm], a1 = As[k][tm + 1], a2 = As[k][tm + 2], a3 = As[k][tm + 3];
            float w0 = Ws[k][tn], w1 = Ws[k][tn + 1], w2 = Ws[k][tn + 2], w3 = Ws[k][tn + 3];
            acc[0][0] += a0 * w0; acc[0][1] += a0 * w1; acc[0][2] += a0 * w2; acc[0][3] += a0 * w3;
            acc[1][0] += a1 * w0; acc[1][1] += a1 * w1; acc[1][2] += a1 * w2; acc[1][3] += a1 * w3;
            acc[2][0] += a2 * w0; acc[2][1] += a2 * w1; acc[2][2] += a2 * w2; acc[2][3] += a2 * w3;
            acc[3][0] += a3 * w0; acc[3][1] += a3 * w1; acc[3][2] += a3 * w2; acc[3][3] += a3 * w3;
        }
        __syncthreads();
    }
    #pragma unroll
    for (int i = 0; i < 4; i++) {
        int m = m0 + tm + i;
        if (m >= M) continue;
        #pragma unroll
        for (int j = 0; j < 4; j++) {
            int n = n0 + tn + j;
            if (n >= N) continue;
            float v = acc[i][j];
            if (bias) v += bias[n];
            if (res)  v += res[(size_t)m * N + n];
            Cto[(size_t)m * N + n] = v;
        }
    }
}

// ---------------- attention: per (b, head) block; K/V head slice in LDS; two-pass softmax
__global__ __launch_bounds__(256) void attn_kernel(const float* __restrict__ q,
        const float* __restrict__ kv, float* __restrict__ attn_cat,
        int L, int hbase)
{
    __shared__ float kb[196 * 12];
    __shared__ float vb[196 * 12];
    int hl = blockIdx.y, b = blockIdx.z;
    int h = hbase + hl;
    for (int idx = threadIdx.x; idx < L * 12; idx += 256) {
        int l = idx / 12, d = idx % 12;
        const float* kp = kv + (size_t)(b * L + l) * 96 + hl * 12 + d;
        kb[idx] = kp[0];
        vb[idx] = kp[48];
    }
    __syncthreads();
    int n = blockIdx.x * 256 + threadIdx.x;
    if (n >= Nc) return;
    float qr[12];
    const float* qp = q + (size_t)(b * Nc + n) * 96 + h * 12;
    #pragma unroll
    for (int d = 0; d < 12; d++) qr[d] = qp[d];
    float mx = -1e30f;
    for (int l = 0; l < L; l++) {
        float s = 0.f;
        #pragma unroll
        for (int d = 0; d < 12; d++) s += qr[d] * kb[l * 12 + d];
        mx = fmaxf(mx, s);
    }
    float mxs = mx * SCALEc;
    float den = 0.f;
    float o[12];
    #pragma unroll
    for (int d = 0; d < 12; d++) o[d] = 0.f;
    for (int l = 0; l < L; l++) {
        float s = 0.f;
        #pragma unroll
        for (int d = 0; d < 12; d++) s += qr[d] * kb[l * 12 + d];
        float e = __expf(s * SCALEc - mxs);
        den += e;
        #pragma unroll
        for (int d = 0; d < 12; d++) o[d] += e * vb[l * 12 + d];
    }
    float rden = 1.f / den;
    float* op = attn_cat + (size_t)(b * Nc + n) * 128 + h * 12;
    #pragma unroll
    for (int d = 0; d < 12; d++) op[d] = o[d] * rden;
}

// ---------------- fused MLP: LN2 + fc1 + gelu + fc2 + residual; 16 rows/block; fp32 out
__global__ __launch_bounds__(256) void mlp_kernel(const float* __restrict__ xres,
        float* __restrict__ dout,
        const float* __restrict__ g, const float* __restrict__ be,
        const float* __restrict__ w1, const float* __restrict__ b1,
        const float* __restrict__ w2, const float* __restrict__ b2)
{
    __shared__ float xr[16][129];
    __shared__ float ml[16][129];
    __shared__ float hid[16][512];
    __shared__ float part[16][128];
    int t = threadIdx.x;
    size_t rbase = (size_t)blockIdx.x * 16;
    for (int i = 0; i < 8; i++) {
        int o = t + i * 256;
        xr[o >> 7][o & 127] = xres[rbase * 128 + o];
    }
    __syncthreads();
    if (t < 16) {
        float s = 0.f, qq = 0.f;
        for (int c2 = 0; c2 < 128; c2++) { float v = xr[t][c2]; s += v; qq += v * v; }
        float mean = s * (1.f / 128.f);
        float inv = rsqrtf(qq * (1.f / 128.f) - mean * mean + EPSc);
        for (int c2 = 0; c2 < 128; c2++)
            ml[t][c2] = (xr[t][c2] - mean) * inv * g[c2] + be[c2];
    }
    __syncthreads();
    float acc0[16], acc1[16];
    #pragma unroll
    for (int r = 0; r < 16; r++) { acc0[r] = 0.f; acc1[r] = 0.f; }
    for (int k = 0; k < 128; k++) {
        float wa = w1[k * 512 + t];
        float wb = w1[k * 512 + t + 256];
        #pragma unroll
        for (int r = 0; r < 16; r++) {
            float m = ml[r][k];
            acc0[r] += m * wa;
            acc1[r] += m * wb;
        }
    }
    float ba = b1[t], bbv = b1[t + 256];
    #pragma unroll
    for (int r = 0; r < 16; r++) {
        hid[r][t] = gelu_f(acc0[r] + ba);
        hid[r][t + 256] = gelu_f(acc1[r] + bbv);
    }
    __syncthreads();
    int c = t & 127, half = t >> 7;
    float a2[16];
    #pragma unroll
    for (int r = 0; r < 16; r++) a2[r] = 0.f;
    int kk0 = half * 256;
    for (int k = kk0; k < kk0 + 256; k++) {
        float wv = w2[k * 128 + c];
        #pragma unroll
        for (int r = 0; r < 16; r++) a2[r] += hid[r][k] * wv;
    }
    if (half == 0) {
        #pragma unroll
        for (int r = 0; r < 16; r++) part[r][c] = a2[r];
    }
    __syncthreads();
    if (half == 1) {
        #pragma unroll
        for (int r = 0; r < 16; r++) part[r][c] += a2[r];
    }
    __syncthreads();
    for (int i = 0; i < 8; i++) {
        int o = t + i * 256;
        int r = o >> 7, cc = o & 127;
        dout[rbase * 128 + o] = xr[r][cc] + part[r][cc] + b2[cc];
    }
}

extern "C" void kernel_launch(void* const* d_in, const int* in_sizes, int n_in,
                              void* d_out, int out_size, void* d_ws, size_t ws_size,
                              hipStream_t stream)
{
    const float* x    = (const float*)d_in[0];
    const float* ln1w = (const float*)d_in[3];
    const float* ln1b = (const float*)d_in[4];
    const float* ln2w = (const float*)d_in[5];
    const float* ln2b = (const float*)d_in[6];
    const float* qw   = (const float*)d_in[7];
    const float* kv1w = (const float*)d_in[8];
    const float* kv2w = (const float*)d_in[9];
    const float* sr1w = (const float*)d_in[10];
    const float* sr1b = (const float*)d_in[11];
    const float* sr2w = (const float*)d_in[12];
    const float* sr2b = (const float*)d_in[13];
    const float* an1w = (const float*)d_in[14];
    const float* an1b = (const float*)d_in[15];
    const float* an2w = (const float*)d_in[16];
    const float* an2b = (const float*)d_in[17];
    const float* wbw  = (const float*)d_in[18];
    const float* wbb  = (const float*)d_in[19];
    const float* wbs  = (const float*)d_in[20];
    const float* wavw = (const float*)d_in[21];
    const float* wavs = (const float*)d_in[22];
    const float* cpw  = (const float*)d_in[23];
    const float* cpb  = (const float*)d_in[24];
    const float* cnw  = (const float*)d_in[25];
    const float* cnb  = (const float*)d_in[26];
    const float* pw   = (const float*)d_in[27];
    const float* pb   = (const float*)d_in[28];
    const float* f1w  = (const float*)d_in[29];
    const float* f1b  = (const float*)d_in[30];
    const float* f2w  = (const float*)d_in[31];
    const float* f2b  = (const float*)d_in[32];
    float* dout = (float*)d_out;
    float* ws = (float*)d_ws;

    // workspace layout (floats)
    float* XA   = ws;                        // 9,633,792  (B,N,96)
    float* QB   = XA  + 9633792;             // 9,633,792  (B,N,96)
    float* ACAT = QB  + 9633792;             // 12,845,056 (B,N,128)
    float* XCI  = ACAT + 12845056;           // 3,211,264  (B,32,56,56)
    float* SUB  = XCI + 3211264;             // 4,296,704  raw subbands, all levels
    float* TT   = SUB + 4296704;             // 4,296,704  conv'd subbands
    float* RA   = TT  + 4296704;             // 3,211,264  recon ping
    float* RB   = RA  + 3211264;             // 3,211,264  recon pong
    float* X1P  = RB  + 3211264;             // 150,528
    float* X2P  = X1P + 150528;              // 602,112
    float* X1B  = X2P + 602112;              // 150,528
    float* X2B  = X1B + 150528;              // 602,112
    float* KV1  = X2B + 602112;              // 150,528
    float* KV2  = KV1 + 150528;              // 602,112
    // overlays (lifetimes disjoint):
    float* XRES = ws;    // (B,N,128) fp32, overlays XA+QB (both dead before proj)
    float* CIMG = SUB;   // (B,32,56,56), SUB dead after wavelet convs
    float* CBUF = TT;    // (B,32,56,56), TT dead after idwt level 0

    float* S0 = SUB;            float* T0 = TT;
    float* S1 = SUB + 3211264;  float* T1 = TT + 3211264;
    float* S2 = SUB + 4014080;  float* T2 = TT + 4014080;
    float* S3 = SUB + 4214784;  float* T3 = TT + 4214784;
    float* S4 = SUB + 4280320;  float* T4 = TT + 4280320;

    // 1. LN1 -> xa + xc_img
    ln1_kernel<<<25088, 256, 0, stream>>>(x, ln1w, ln1b, XA, XCI);

    // 2. DWT cascade (raw subbands; next level reads raw LL at channel stride 4)
    dwt_kernel<<<3136, 256, 0, stream>>>(XCI, 1, 56, 56, 28, 28, S0);
    dwt_kernel<<<784,  256, 0, stream>>>(S0, 4, 28, 28, 14, 14, S1);
    dwt_kernel<<<196,  256, 0, stream>>>(S1, 4, 14, 14, 7, 7,   S2);
    dwt_kernel<<<64,   256, 0, stream>>>(S2, 4, 7, 7,   4, 4,   S3);
    dwt_kernel<<<16,   256, 0, stream>>>(S3, 4, 4, 4,   2, 2,   S4);

    // 3. wavelet depthwise convs (+scale)
    dw3x3_kernel<<<12544, 256, 0, stream>>>(S0, wavw,        wavs,       nullptr, nullptr, T0, 128, 28, 28);
    dw3x3_kernel<<<3136,  256, 0, stream>>>(S1, wavw + 1152, wavs + 128, nullptr, nullptr, T1, 128, 14, 14);
    dw3x3_kernel<<<784,   256, 0, stream>>>(S2, wavw + 2304, wavs + 256, nullptr, nullptr, T2, 128, 7, 7);
    dw3x3_kernel<<<256,   256, 0, stream>>>(S3, wavw + 3456, wavs + 384, nullptr, nullptr, T3, 128, 4, 4);
    dw3x3_kernel<<<64,    256, 0, stream>>>(S4, wavw + 4608, wavs + 512, nullptr, nullptr, T4, 128, 2, 2);

    // 4. IDWT cascade with accumulate + crop
    idwt_kernel<<<64,    256, 0, stream>>>(T4, nullptr, RA, 2, 2, 4, 4);
    idwt_kernel<<<196,   256, 0, stream>>>(T3, RA, RB, 4, 4, 7, 7);
    idwt_kernel<<<784,   256, 0, stream>>>(T2, RB, RA, 7, 7, 14, 14);
    idwt_kernel<<<3136,  256, 0, stream>>>(T1, RA, RB, 14, 14, 28, 28);
    idwt_kernel<<<12544, 256, 0, stream>>>(T0, RB, RA, 28, 28, 56, 56);

    // 5. base depthwise conv (+bias, *scale, +recon)
    dw3x3_kernel<<<12544, 256, 0, stream>>>(XCI, wbw, wbs, wbb, RA, CIMG, 32, 56, 56);

    // 6. cp2d 3x3 full conv
    cp2d_kernel<<<12544, 256, 0, stream>>>(CIMG, cpw, cpb, CBUF);

    // 7. channel LN(32) + gelu -> attn_cat[96:128]
    cn_kernel<<<392, 256, 0, stream>>>(CBUF, cnw, cnb, ACAT);

    // 8/9. spatial reductions (stride 8 / 4), output (B,L,96)
    sr_kernel<<<588,  256, 0, stream>>>(XA, sr1w, sr1b, X1P, 8, 7);
    sr_kernel<<<2352, 256, 0, stream>>>(XA, sr2w, sr2b, X2P, 4, 14);

    // 10. LN96 + gelu
    ln96_kernel<<<392,  256, 0, stream>>>(X1P, an1w, an1b, X1B, 1568);
    ln96_kernel<<<1568, 256, 0, stream>>>(X2P, an2w, an2b, X2B, 6272);

    // 11. q / kv matmuls
    matmul_kernel<<<dim3(2, 1568), 256, 0, stream>>>(XA,  qw,   nullptr, nullptr, QB,  100352, 96, 96);
    matmul_kernel<<<dim3(2, 25),   256, 0, stream>>>(X1B, kv1w, nullptr, nullptr, KV1, 1568,   96, 96);
    matmul_kernel<<<dim3(2, 98),   256, 0, stream>>>(X2B, kv2w, nullptr, nullptr, KV2, 6272,   96, 96);

    // 12. attention branches -> attn_cat[0:96]
    attn_kernel<<<dim3(13, 4, 32), 256, 0, stream>>>(QB, KV1, ACAT, 49, 0);
    attn_kernel<<<dim3(13, 4, 32), 256, 0, stream>>>(QB, KV2, ACAT, 196, 4);

    // 13. proj + bias + residual(x) -> XRES (fp32)
    matmul_kernel<<<dim3(2, 1568), 256, 0, stream>>>(ACAT, pw, pb, x, XRES, 100352, 128, 128);

    // 14. fused LN2 + MLP + residual -> d_out (fp32)
    mlp_kernel<<<6272, 256, 0, stream>>>(XRES, dout, ln2w, ln2b, f1w, f1b, f2w, f2b);
}

// Round 3
// 1033.704 us; speedup vs baseline: 1.5250x; 1.5250x over previous
//
#include <hip/hip_runtime.h>
#include <hip/hip_bf16.h>
#include <math.h>

typedef __hip_bfloat16 bf16;
typedef __attribute__((ext_vector_type(8))) short bf16x8;
typedef __attribute__((ext_vector_type(4))) float f32x4;

#define Bc   32
#define Hc   56
#define Wcc  56
#define Nc   3136
#define Cpc  32
#define Cac  96
#define EPSc 1e-5f
#define SCALEc 0.28867513459481287f   /* 1/sqrt(12) */

__device__ __forceinline__ float gelu_f(float x) {
    return 0.5f * x * (1.0f + erff(x * 0.7071067811865475f));
}

// ---------------- LN1: (B,N,128) -> xa fp32 (B,N,96) + xab bf16 + xc_img (B,32,56,56) fp32
__global__ __launch_bounds__(256) void ln1_kernel(const float* __restrict__ x,
        const float* __restrict__ g, const float* __restrict__ be,
        float* __restrict__ xa, bf16* __restrict__ xab, float* __restrict__ xc_img)
{
    int wv = threadIdx.x >> 6, lane = threadIdx.x & 63;
    int row = blockIdx.x * 4 + wv;
    if (row >= Bc * Nc) return;
    const float* xr = x + (size_t)row * 128;
    float x0 = xr[lane];
    float x1 = xr[lane + 64];
    float s = x0 + x1, q = x0 * x0 + x1 * x1;
    for (int o = 32; o; o >>= 1) { s += __shfl_xor(s, o); q += __shfl_xor(q, o); }
    float mean = s * (1.f / 128.f);
    float inv = rsqrtf(q * (1.f / 128.f) - mean * mean + EPSc);
    int b = row / Nc, n = row % Nc;
    {
        int c = lane;
        float y = (x0 - mean) * inv * g[c] + be[c];
        if (c < Cpc) xc_img[(size_t)(b * Cpc + c) * Nc + n] = y;
        else { xa[(size_t)row * Cac + (c - Cpc)] = y;
               xab[(size_t)row * Cac + (c - Cpc)] = __float2bfloat16(y); }
    }
    {
        int c = lane + 64;
        float y = (x1 - mean) * inv * g[c] + be[c];
        xa[(size_t)row * Cac + (c - Cpc)] = y;
        xab[(size_t)row * Cac + (c - Cpc)] = __float2bfloat16(y);
    }
}

// ---------------- Haar DWT
__global__ void dwt_kernel(const float* __restrict__ src, int cs, int h, int w,
                           int h2, int w2, float* __restrict__ sub)
{
    int t = blockIdx.x * blockDim.x + threadIdx.x;
    int total = Bc * 32 * h2 * w2;
    if (t >= total) return;
    int xx = t % w2; int r = t / w2;
    int yy = r % h2; r /= h2;
    int c = r & 31; int b = r >> 5;
    const float* sp = src + (size_t)cs * (b * 32 + c) * h * w;
    int y0 = yy * 2, x0 = xx * 2;
    bool xe = (x0 + 1 < w), ye = (y0 + 1 < h);
    float a  = sp[y0 * w + x0];
    float bb = xe ? sp[y0 * w + x0 + 1] : 0.f;
    float cc = ye ? sp[(y0 + 1) * w + x0] : 0.f;
    float dd = (xe && ye) ? sp[(y0 + 1) * w + x0 + 1] : 0.f;
    size_t pl = (size_t)h2 * w2;
    size_t ob = (size_t)(b * 128 + c * 4) * pl + yy * w2 + xx;
    sub[ob]          = ( a + bb + cc + dd) * 0.5f;
    sub[ob + pl]     = (-a - bb + cc + dd) * 0.5f;
    sub[ob + 2 * pl] = (-a + bb - cc + dd) * 0.5f;
    sub[ob + 3 * pl] = ( a - bb - cc + dd) * 0.5f;
}

// ---------------- depthwise 3x3 SAME
__global__ void dw3x3_kernel(const float* __restrict__ src, const float* __restrict__ wt,
        const float* __restrict__ scale, const float* __restrict__ bias,
        const float* __restrict__ addb, float* __restrict__ dst,
        int C, int h, int w)
{
    int t = blockIdx.x * blockDim.x + threadIdx.x;
    int total = Bc * C * h * w;
    if (t >= total) return;
    int x = t % w; int r = t / w;
    int y = r % h; r /= h;
    int c = r % C;
    const float* sp = src + (size_t)(t - x - y * w);
    float acc = 0.f;
    #pragma unroll
    for (int u = 0; u < 3; u++) {
        int yy = y + u - 1;
        if (yy < 0 || yy >= h) continue;
        #pragma unroll
        for (int v = 0; v < 3; v++) {
            int xx = x + v - 1;
            if (xx < 0 || xx >= w) continue;
            acc += sp[yy * w + xx] * wt[(u * 3 + v) * C + c];
        }
    }
    if (bias) acc += bias[c];
    acc *= scale[c];
    if (addb) acc += addb[t];
    dst[t] = acc;
}

// ---------------- Haar IDWT (+ll add, crop)
__global__ void idwt_kernel(const float* __restrict__ tl, const float* __restrict__ nxt,
        float* __restrict__ outp, int h2, int w2, int ho, int wo)
{
    int t = blockIdx.x * blockDim.x + threadIdx.x;
    int total = Bc * 32 * ho * wo;
    if (t >= total) return;
    int x = t % wo; int r = t / wo;
    int y = r % ho; r /= ho;
    int c = r & 31; int b = r >> 5;
    int y2 = y >> 1, x2 = x >> 1;
    size_t pl = (size_t)h2 * w2;
    size_t base = (size_t)(b * 128 + c * 4) * pl + y2 * w2 + x2;
    float ll = tl[base];
    if (nxt) ll += nxt[(size_t)(b * 32 + c) * pl + y2 * w2 + x2];
    float lh = tl[base + pl], hl = tl[base + 2 * pl], hh = tl[base + 3 * pl];
    float v;
    if ((y & 1) == 0) v = ((x & 1) == 0) ? (ll - lh - hl + hh) : (ll - lh + hl - hh);
    else              v = ((x & 1) == 0) ? (ll + lh - hl - hh) : (ll + lh + hl + hh);
    outp[t] = v * 0.5f;
}

// ---------------- cp2d: full 3x3 conv 32->32 SAME, weight HWIO (3,3,32,32)
__global__ void cp2d_kernel(const float* __restrict__ src, const float* __restrict__ wt,
        const float* __restrict__ bias, float* __restrict__ dst)
{
    int t = blockIdx.x * blockDim.x + threadIdx.x;
    int total = Bc * 32 * Nc;
    if (t >= total) return;
    int x = t % Wcc; int r = t / Wcc;
    int y = r % Hc; r /= Hc;
    int co = r & 31; int b = r >> 5;
    const float* sp0 = src + (size_t)b * 32 * Nc;
    float acc = bias[co];
    #pragma unroll
    for (int u = 0; u < 3; u++) {
        int yy = y + u - 1;
        if (yy < 0 || yy >= Hc) continue;
        #pragma unroll
        for (int v = 0; v < 3; v++) {
            int xx = x + v - 1;
            if (xx < 0 || xx >= Wcc) continue;
            const float* sp = sp0 + yy * Wcc + xx;
            const float* wp = wt + ((u * 3 + v) * 32) * 32 + co;
            #pragma unroll
            for (int ci = 0; ci < 32; ci++)
                acc += sp[(size_t)ci * Nc] * wp[ci * 32];
        }
    }
    dst[t] = acc;
}

// ---------------- cn: LN over 32 ch + gelu -> bf16 attn_cat cols 96..127
__global__ void cn_kernel(const float* __restrict__ cb, const float* __restrict__ g,
        const float* __restrict__ be, bf16* __restrict__ attn_cat)
{
    int t = blockIdx.x * blockDim.x + threadIdx.x;
    if (t >= Bc * Nc) return;
    int b = t / Nc, n = t % Nc;
    const float* p = cb + (size_t)b * 32 * Nc + n;
    float v[32]; float s = 0.f;
    #pragma unroll
    for (int c = 0; c < 32; c++) { v[c] = p[(size_t)c * Nc]; s += v[c]; }
    float mean = s * (1.f / 32.f), q = 0.f;
    #pragma unroll
    for (int c = 0; c < 32; c++) { float d = v[c] - mean; q += d * d; }
    float inv = rsqrtf(q * (1.f / 32.f) + EPSc);
    bf16* o = attn_cat + (size_t)t * 128 + 96;
    #pragma unroll
    for (int c = 0; c < 32; c++)
        o[c] = __float2bfloat16(gelu_f((v[c] - mean) * inv * g[c] + be[c]));
}

// ---------------- sr: depthwise ks x ks stride ks VALID; out (B,L,96) fp32
__global__ void sr_kernel(const float* __restrict__ xa, const float* __restrict__ wt,
        const float* __restrict__ bias, float* __restrict__ outp, int ks, int Ld)
{
    int t = blockIdx.x * blockDim.x + threadIdx.x;
    int total = Bc * Ld * Ld * Cac;
    if (t >= total) return;
    int c = t % Cac; int r = t / Cac;
    int j = r % Ld; r /= Ld;
    int i = r % Ld; int b = r / Ld;
    float acc = bias[c];
    for (int u = 0; u < ks; u++)
        for (int v = 0; v < ks; v++)
            acc += xa[(size_t)(b * Nc + (i * ks + u) * Wcc + (j * ks + v)) * Cac + c]
                 * wt[(u * ks + v) * Cac + c];
    outp[t] = acc;
}

// ---------------- LN over 96 + gelu -> bf16
__global__ __launch_bounds__(256) void ln96_kernel(const float* __restrict__ src,
        const float* __restrict__ g, const float* __restrict__ be,
        bf16* __restrict__ dst, int R)
{
    int wv = threadIdx.x >> 6, lane = threadIdx.x & 63;
    int row = blockIdx.x * 4 + wv;
    if (row >= R) return;
    const float* sp = src + (size_t)row * 96;
    float x0 = sp[lane];
    float x1 = (lane < 32) ? sp[64 + lane] : 0.f;
    float s = x0 + x1, q = x0 * x0 + x1 * x1;
    for (int o = 32; o; o >>= 1) { s += __shfl_xor(s, o); q += __shfl_xor(q, o); }
    float mean = s * (1.f / 96.f);
    float inv = rsqrtf(q * (1.f / 96.f) - mean * mean + EPSc);
    dst[(size_t)row * 96 + lane] =
        __float2bfloat16(gelu_f((x0 - mean) * inv * g[lane] + be[lane]));
    if (lane < 32)
        dst[(size_t)row * 96 + 64 + lane] =
            __float2bfloat16(gelu_f((x1 - mean) * inv * g[64 + lane] + be[64 + lane]));
}

// ---------------- LN2: (B,N,128) fp32 -> bf16
__global__ __launch_bounds__(256) void ln2_kernel(const float* __restrict__ xres,
        const float* __restrict__ g, const float* __restrict__ be,
        bf16* __restrict__ xnb)
{
    int wv = threadIdx.x >> 6, lane = threadIdx.x & 63;
    int row = blockIdx.x * 4 + wv;
    if (row >= Bc * Nc) return;
    const float* xr = xres + (size_t)row * 128;
    float x0 = xr[lane], x1 = xr[lane + 64];
    float s = x0 + x1, q = x0 * x0 + x1 * x1;
    for (int o = 32; o; o >>= 1) { s += __shfl_xor(s, o); q += __shfl_xor(q, o); }
    float mean = s * (1.f / 128.f);
    float inv = rsqrtf(q * (1.f / 128.f) - mean * mean + EPSc);
    xnb[(size_t)row * 128 + lane] =
        __float2bfloat16((x0 - mean) * inv * g[lane] + be[lane]);
    xnb[(size_t)row * 128 + lane + 64] =
        __float2bfloat16((x1 - mean) * inv * g[lane + 64] + be[lane + 64]);
}

// ---------------- weight transpose + convert: in (K,N) fp32 -> out (N,K) bf16
__global__ void wtrans_kernel(const float* __restrict__ in, bf16* __restrict__ out,
                              int K, int N)
{
    int t = blockIdx.x * blockDim.x + threadIdx.x;
    if (t >= K * N) return;
    int n = t % N, k = t / N;
    out[(size_t)n * K + k] = __float2bfloat16(in[t]);
}

// ---------------- MFMA GEMM: out(MxNt) = A(MxK bf16) x Wt(NtxK bf16)^T [+bias][gelu][+res fp32]
// tile: 64 x (16*NF); 256 threads = 4 waves; 16x16x32 bf16 MFMA
template<int NF, bool GELU, bool RES, bool OUTBF>
__global__ __launch_bounds__(256) void gemm_kernel(const bf16* __restrict__ A,
        const bf16* __restrict__ Wt, const float* __restrict__ bias,
        const float* __restrict__ res, void* __restrict__ outp,
        int M, int K, int Nt)
{
    constexpr int TN = 16 * NF;
    __shared__ unsigned short As[64][40];
    __shared__ unsigned short Bs[TN][40];
    int tid = threadIdx.x;
    int wave = tid >> 6, lane = tid & 63;
    int m0 = blockIdx.y * 64, n0 = blockIdx.x * TN;
    f32x4 acc[NF];
    #pragma unroll
    for (int f = 0; f < NF; f++) acc[f] = (f32x4){0.f, 0.f, 0.f, 0.f};

    int ar = tid >> 2, ac = (tid & 3) << 3;
    int ml = wave * 16 + (lane & 15);
    int qd = lane >> 4;

    for (int k0 = 0; k0 < K; k0 += 32) {
        int4 av = make_int4(0, 0, 0, 0);
        if (m0 + ar < M) av = *(const int4*)(A + (size_t)(m0 + ar) * K + k0 + ac);
        *(int4*)&As[ar][ac] = av;
        for (int idx = tid; idx < TN * 4; idx += 256) {
            int br = idx >> 2, bc = (idx & 3) << 3;
            *(int4*)&Bs[br][bc] = *(const int4*)(Wt + (size_t)(n0 + br) * K + k0 + bc);
        }
        __syncthreads();
        bf16x8 af = *(const bf16x8*)&As[ml][qd * 8];
        #pragma unroll
        for (int f = 0; f < NF; f++) {
            bf16x8 bfv = *(const bf16x8*)&Bs[f * 16 + (lane & 15)][qd * 8];
            acc[f] = __builtin_amdgcn_mfma_f32_16x16x32_bf16(af, bfv, acc[f], 0, 0, 0);
        }
        __syncthreads();
    }
    #pragma unroll
    for (int f = 0; f < NF; f++) {
        int n = n0 + f * 16 + (lane & 15);
        #pragma unroll
        for (int r = 0; r < 4; r++) {
            int m = m0 + wave * 16 + qd * 4 + r;
            if (m >= M) continue;
            float v = acc[f][r];
            if (bias) v += bias[n];
            if (GELU) v = gelu_f(v);
            if (RES)  v += res[(size_t)m * Nt + n];
            if (OUTBF) ((bf16*)outp)[(size_t)m * Nt + n] = __float2bfloat16(v);
            else       ((float*)outp)[(size_t)m * Nt + n] = v;
        }
    }
}

// ---------------- attention: per (b, head) block; K/V in LDS; writes bf16 attn_cat
__global__ __launch_bounds__(256) void attn_kernel(const float* __restrict__ q,
        const float* __restrict__ kv, bf16* __restrict__ attn_cat,
        int L, int hbase)
{
    __shared__ float kb[196 * 12];
    __shared__ float vb[196 * 12];
    int hl = blockIdx.y, b = blockIdx.z;
    int h = hbase + hl;
    for (int idx = threadIdx.x; idx < L * 12; idx += 256) {
        int l = idx / 12, d = idx % 12;
        const float* kp = kv + (size_t)(b * L + l) * 96 + hl * 12 + d;
        kb[idx] = kp[0];
        vb[idx] = kp[48];
    }
    __syncthreads();
    int n = blockIdx.x * 256 + threadIdx.x;
    if (n >= Nc) return;
    float qr[12];
    const float* qp = q + (size_t)(b * Nc + n) * 96 + h * 12;
    #pragma unroll
    for (int d = 0; d < 12; d++) qr[d] = qp[d];
    float mx = -1e30f;
    for (int l = 0; l < L; l++) {
        float s = 0.f;
        #pragma unroll
        for (int d = 0; d < 12; d++) s += qr[d] * kb[l * 12 + d];
        mx = fmaxf(mx, s);
    }
    float mxs = mx * SCALEc;
    float den = 0.f;
    float o[12];
    #pragma unroll
    for (int d = 0; d < 12; d++) o[d] = 0.f;
    for (int l = 0; l < L; l++) {
        float s = 0.f;
        #pragma unroll
        for (int d = 0; d < 12; d++) s += qr[d] * kb[l * 12 + d];
        float e = __expf(s * SCALEc - mxs);
        den += e;
        #pragma unroll
        for (int d = 0; d < 12; d++) o[d] += e * vb[l * 12 + d];
    }
    float rden = 1.f / den;
    bf16* op = attn_cat + (size_t)(b * Nc + n) * 128 + h * 12;
    #pragma unroll
    for (int d = 0; d < 12; d++) op[d] = __float2bfloat16(o[d] * rden);
}

extern "C" void kernel_launch(void* const* d_in, const int* in_sizes, int n_in,
                              void* d_out, int out_size, void* d_ws, size_t ws_size,
                              hipStream_t stream)
{
    const float* x    = (const float*)d_in[0];
    const float* ln1w = (const float*)d_in[3];
    const float* ln1b = (const float*)d_in[4];
    const float* ln2w = (const float*)d_in[5];
    const float* ln2b = (const float*)d_in[6];
    const float* qw   = (const float*)d_in[7];
    const float* kv1w = (const float*)d_in[8];
    const float* kv2w = (const float*)d_in[9];
    const float* sr1w = (const float*)d_in[10];
    const float* sr1b = (const float*)d_in[11];
    const float* sr2w = (const float*)d_in[12];
    const float* sr2b = (const float*)d_in[13];
    const float* an1w = (const float*)d_in[14];
    const float* an1b = (const float*)d_in[15];
    const float* an2w = (const float*)d_in[16];
    const float* an2b = (const float*)d_in[17];
    const float* wbw  = (const float*)d_in[18];
    const float* wbb  = (const float*)d_in[19];
    const float* wbs  = (const float*)d_in[20];
    const float* wavw = (const float*)d_in[21];
    const float* wavs = (const float*)d_in[22];
    const float* cpw  = (const float*)d_in[23];
    const float* cpb  = (const float*)d_in[24];
    const float* cnw  = (const float*)d_in[25];
    const float* cnb  = (const float*)d_in[26];
    const float* pw   = (const float*)d_in[27];
    const float* pb   = (const float*)d_in[28];
    const float* f1w  = (const float*)d_in[29];
    const float* f1b  = (const float*)d_in[30];
    const float* f2w  = (const float*)d_in[31];
    const float* f2b  = (const float*)d_in[32];
    float* dout = (float*)d_out;
    float* ws = (float*)d_ws;

    // workspace layout (float offsets; all 16B-aligned)
    float* XA    = ws;                      // 9,633,792
    float* QB    = ws + 9633792;            // 9,633,792 -> 19,267,584
    float* XRES  = ws;                      // 12,845,056 overlay (XA + QB head; both dead by proj)
    bf16*  XNb   = (bf16*)(ws + 12845056);  // 12,845,056 bf16 -> float end 19,267,584 (QB tail; dead by ln2)
    bf16*  XAb   = (bf16*)(ws + 19267584);  // 9,633,792 bf16  (4,816,896 f)
    bf16*  ACATb = (bf16*)(ws + 24084480);  // 12,845,056 bf16 (6,422,528 f)
    float* XCI   = ws + 30507008;           // 3,211,264
    float* SUB   = ws + 33718272;           // 4,296,704
    float* TT    = ws + 38014976;           // 4,296,704
    float* RA    = ws + 42311680;           // 3,211,264
    float* RB    = ws + 45522944;           // 3,211,264
    float* X1P   = ws + 48734208;           // 150,528
    float* X2P   = ws + 48884736;           // 602,112
    bf16*  X1Bb  = (bf16*)(ws + 49486848);  // 150,528 bf16
    bf16*  X2Bb  = (bf16*)(ws + 49562112);  // 602,112 bf16
    float* KV1   = ws + 49863168;           // 150,528
    float* KV2   = ws + 50013696;           // 602,112
    bf16*  WTB   = (bf16*)(ws + 50615808);  // 175,104 bf16 -> total 50,703,360 f (~203MB)
    bf16*  qwt   = WTB;
    bf16*  kv1wt = WTB + 9216;
    bf16*  kv2wt = WTB + 18432;
    bf16*  pwt   = WTB + 27648;
    bf16*  w1t   = WTB + 44032;
    bf16*  w2t   = WTB + 109568;
    bf16*  Hb    = (bf16*)(ws + 24084480);  // 51,380,224 bf16 overlay (ACATb..X2Bb; all dead by fc1)
    // overlays in WT path:
    float* CIMG = SUB;
    float* CBUF = TT;
    float* S0 = SUB;            float* T0 = TT;
    float* S1 = SUB + 3211264;  float* T1 = TT + 3211264;
    float* S2 = SUB + 4014080;  float* T2 = TT + 4014080;
    float* S3 = SUB + 4214784;  float* T3 = TT + 4214784;
    float* S4 = SUB + 4280320;  float* T4 = TT + 4280320;

    // 0. weight transposes (fp32 -> bf16, N-major)
    wtrans_kernel<<<36,  256, 0, stream>>>(qw,   qwt,   96, 96);
    wtrans_kernel<<<36,  256, 0, stream>>>(kv1w, kv1wt, 96, 96);
    wtrans_kernel<<<36,  256, 0, stream>>>(kv2w, kv2wt, 96, 96);
    wtrans_kernel<<<64,  256, 0, stream>>>(pw,   pwt,   128, 128);
    wtrans_kernel<<<256, 256, 0, stream>>>(f1w,  w1t,   128, 512);
    wtrans_kernel<<<256, 256, 0, stream>>>(f2w,  w2t,   512, 128);

    // 1. LN1
    ln1_kernel<<<25088, 256, 0, stream>>>(x, ln1w, ln1b, XA, XAb, XCI);

    // 2. DWT cascade
    dwt_kernel<<<3136, 256, 0, stream>>>(XCI, 1, 56, 56, 28, 28, S0);
    dwt_kernel<<<784,  256, 0, stream>>>(S0, 4, 28, 28, 14, 14, S1);
    dwt_kernel<<<196,  256, 0, stream>>>(S1, 4, 14, 14, 7, 7,   S2);
    dwt_kernel<<<64,   256, 0, stream>>>(S2, 4, 7, 7,   4, 4,   S3);
    dwt_kernel<<<16,   256, 0, stream>>>(S3, 4, 4, 4,   2, 2,   S4);

    // 3. wavelet depthwise convs
    dw3x3_kernel<<<12544, 256, 0, stream>>>(S0, wavw,        wavs,       nullptr, nullptr, T0, 128, 28, 28);
    dw3x3_kernel<<<3136,  256, 0, stream>>>(S1, wavw + 1152, wavs + 128, nullptr, nullptr, T1, 128, 14, 14);
    dw3x3_kernel<<<784,   256, 0, stream>>>(S2, wavw + 2304, wavs + 256, nullptr, nullptr, T2, 128, 7, 7);
    dw3x3_kernel<<<256,   256, 0, stream>>>(S3, wavw + 3456, wavs + 384, nullptr, nullptr, T3, 128, 4, 4);
    dw3x3_kernel<<<64,    256, 0, stream>>>(S4, wavw + 4608, wavs + 512, nullptr, nullptr, T4, 128, 2, 2);

    // 4. IDWT cascade
    idwt_kernel<<<64,    256, 0, stream>>>(T4, nullptr, RA, 2, 2, 4, 4);
    idwt_kernel<<<196,   256, 0, stream>>>(T3, RA, RB, 4, 4, 7, 7);
    idwt_kernel<<<784,   256, 0, stream>>>(T2, RB, RA, 7, 7, 14, 14);
    idwt_kernel<<<3136,  256, 0, stream>>>(T1, RA, RB, 14, 14, 28, 28);
    idwt_kernel<<<12544, 256, 0, stream>>>(T0, RB, RA, 28, 28, 56, 56);

    // 5. base depthwise conv
    dw3x3_kernel<<<12544, 256, 0, stream>>>(XCI, wbw, wbs, wbb, RA, CIMG, 32, 56, 56);

    // 6. cp2d
    cp2d_kernel<<<12544, 256, 0, stream>>>(CIMG, cpw, cpb, CBUF);

    // 7. cn -> ACATb[96:128]
    cn_kernel<<<392, 256, 0, stream>>>(CBUF, cnw, cnb, ACATb);

    // 8/9. spatial reductions
    sr_kernel<<<588,  256, 0, stream>>>(XA, sr1w, sr1b, X1P, 8, 7);
    sr_kernel<<<2352, 256, 0, stream>>>(XA, sr2w, sr2b, X2P, 4, 14);

    // 10. LN96 + gelu -> bf16
    ln96_kernel<<<392,  256, 0, stream>>>(X1P, an1w, an1b, X1Bb, 1568);
    ln96_kernel<<<1568, 256, 0, stream>>>(X2P, an2w, an2b, X2Bb, 6272);

    // 11. q / kv GEMMs (MFMA)
    gemm_kernel<6,false,false,false><<<dim3(1, 1568), 256, 0, stream>>>(XAb,  qwt,   nullptr, nullptr, QB,  100352, 96, 96);
    gemm_kernel<6,false,false,false><<<dim3(1, 25),   256, 0, stream>>>(X1Bb, kv1wt, nullptr, nullptr, KV1, 1568,   96, 96);
    gemm_kernel<6,false,false,false><<<dim3(1, 98),   256, 0, stream>>>(X2Bb, kv2wt, nullptr, nullptr, KV2, 6272,   96, 96);

    // 12. attention -> ACATb[0:96]
    attn_kernel<<<dim3(13, 4, 32), 256, 0, stream>>>(QB, KV1, ACATb, 49, 0);
    attn_kernel<<<dim3(13, 4, 32), 256, 0, stream>>>(QB, KV2, ACATb, 196, 4);

    // 13. proj + bias + residual(x) -> XRES fp32
    gemm_kernel<4,false,true,false><<<dim3(2, 1568), 256, 0, stream>>>(ACATb, pwt, pb, x, XRES, 100352, 128, 128);

    // 14. LN2 -> bf16
    ln2_kernel<<<25088, 256, 0, stream>>>(XRES, ln2w, ln2b, XNb);

    // 15. fc1 + bias + gelu -> Hb bf16
    gemm_kernel<4,true,false,true><<<dim3(8, 1568), 256, 0, stream>>>(XNb, w1t, f1b, nullptr, Hb, 100352, 128, 512);

    // 16. fc2 + bias + residual(XRES) -> d_out fp32
    gemm_kernel<4,false,true,false><<<dim3(2, 1568), 256, 0, stream>>>(Hb, w2t, f2b, XRES, dout, 100352, 512, 128);
}

// Round 4
// 773.749 us; speedup vs baseline: 2.0373x; 1.3360x over previous
//
#include <hip/hip_runtime.h>
#include <hip/hip_bf16.h>
#include <math.h>

typedef __hip_bfloat16 bf16;
typedef __attribute__((ext_vector_type(8))) short bf16x8;
typedef __attribute__((ext_vector_type(4))) float f32x4;

#define Bc   32
#define Hc   56
#define Wcc  56
#define Nc   3136
#define Cpc  32
#define Cac  96
#define EPSc 1e-5f
#define SCALEc 0.28867513459481287f   /* 1/sqrt(12) */

__device__ __forceinline__ float gelu_f(float x) {
    return 0.5f * x * (1.0f + erff(x * 0.7071067811865475f));
}

// ---------------- LN1: (B,N,128) -> xa fp32 (B,N,96) + xab bf16 + xc_img (B,32,56,56) fp32
__global__ __launch_bounds__(256) void ln1_kernel(const float* __restrict__ x,
        const float* __restrict__ g, const float* __restrict__ be,
        float* __restrict__ xa, bf16* __restrict__ xab, float* __restrict__ xc_img)
{
    int wv = threadIdx.x >> 6, lane = threadIdx.x & 63;
    int row = blockIdx.x * 4 + wv;
    if (row >= Bc * Nc) return;
    const float* xr = x + (size_t)row * 128;
    float x0 = xr[lane];
    float x1 = xr[lane + 64];
    float s = x0 + x1, q = x0 * x0 + x1 * x1;
    for (int o = 32; o; o >>= 1) { s += __shfl_xor(s, o); q += __shfl_xor(q, o); }
    float mean = s * (1.f / 128.f);
    float inv = rsqrtf(q * (1.f / 128.f) - mean * mean + EPSc);
    int b = row / Nc, n = row % Nc;
    {
        int c = lane;
        float y = (x0 - mean) * inv * g[c] + be[c];
        if (c < Cpc) xc_img[(size_t)(b * Cpc + c) * Nc + n] = y;
        else { xa[(size_t)row * Cac + (c - Cpc)] = y;
               xab[(size_t)row * Cac + (c - Cpc)] = __float2bfloat16(y); }
    }
    {
        int c = lane + 64;
        float y = (x1 - mean) * inv * g[c] + be[c];
        xa[(size_t)row * Cac + (c - Cpc)] = y;
        xab[(size_t)row * Cac + (c - Cpc)] = __float2bfloat16(y);
    }
}

// ---------------- Haar DWT
__global__ void dwt_kernel(const float* __restrict__ src, int cs, int h, int w,
                           int h2, int w2, float* __restrict__ sub)
{
    int t = blockIdx.x * blockDim.x + threadIdx.x;
    int total = Bc * 32 * h2 * w2;
    if (t >= total) return;
    int xx = t % w2; int r = t / w2;
    int yy = r % h2; r /= h2;
    int c = r & 31; int b = r >> 5;
    const float* sp = src + (size_t)cs * (b * 32 + c) * h * w;
    int y0 = yy * 2, x0 = xx * 2;
    bool xe = (x0 + 1 < w), ye = (y0 + 1 < h);
    float a  = sp[y0 * w + x0];
    float bb = xe ? sp[y0 * w + x0 + 1] : 0.f;
    float cc = ye ? sp[(y0 + 1) * w + x0] : 0.f;
    float dd = (xe && ye) ? sp[(y0 + 1) * w + x0 + 1] : 0.f;
    size_t pl = (size_t)h2 * w2;
    size_t ob = (size_t)(b * 128 + c * 4) * pl + yy * w2 + xx;
    sub[ob]          = ( a + bb + cc + dd) * 0.5f;
    sub[ob + pl]     = (-a - bb + cc + dd) * 0.5f;
    sub[ob + 2 * pl] = (-a + bb - cc + dd) * 0.5f;
    sub[ob + 3 * pl] = ( a - bb - cc + dd) * 0.5f;
}

// ---------------- depthwise 3x3 SAME (generic, fp32 out)
__global__ void dw3x3_kernel(const float* __restrict__ src, const float* __restrict__ wt,
        const float* __restrict__ scale, const float* __restrict__ bias,
        const float* __restrict__ addb, float* __restrict__ dst,
        int C, int h, int w)
{
    int t = blockIdx.x * blockDim.x + threadIdx.x;
    int total = Bc * C * h * w;
    if (t >= total) return;
    int x = t % w; int r = t / w;
    int y = r % h; r /= h;
    int c = r % C;
    const float* sp = src + (size_t)(t - x - y * w);
    float acc = 0.f;
    #pragma unroll
    for (int u = 0; u < 3; u++) {
        int yy = y + u - 1;
        if (yy < 0 || yy >= h) continue;
        #pragma unroll
        for (int v = 0; v < 3; v++) {
            int xx = x + v - 1;
            if (xx < 0 || xx >= w) continue;
            acc += sp[yy * w + xx] * wt[(u * 3 + v) * C + c];
        }
    }
    if (bias) acc += bias[c];
    acc *= scale[c];
    if (addb) acc += addb[t];
    dst[t] = acc;
}

// ---------------- base depthwise 3x3 + bias, *scale, +recon -> bf16 NHWC (B,56,56,32)
__global__ void dwbase_kernel(const float* __restrict__ src, const float* __restrict__ wt,
        const float* __restrict__ scale, const float* __restrict__ bias,
        const float* __restrict__ addb, bf16* __restrict__ dst_nhwc)
{
    int t = blockIdx.x * blockDim.x + threadIdx.x;
    int total = Bc * 32 * Nc;
    if (t >= total) return;
    int x = t % Wcc; int r = t / Wcc;
    int y = r % Hc; r /= Hc;
    int c = r & 31; int b = r >> 5;
    const float* sp = src + (size_t)(t - x - y * Wcc);
    float acc = 0.f;
    #pragma unroll
    for (int u = 0; u < 3; u++) {
        int yy = y + u - 1;
        if (yy < 0 || yy >= Hc) continue;
        #pragma unroll
        for (int v = 0; v < 3; v++) {
            int xx = x + v - 1;
            if (xx < 0 || xx >= Wcc) continue;
            acc += sp[yy * Wcc + xx] * wt[(u * 3 + v) * 32 + c];
        }
    }
    acc = (acc + bias[c]) * scale[c] + addb[t];
    dst_nhwc[(((size_t)b * Hc + y) * Wcc + x) * 32 + c] = __float2bfloat16(acc);
}

// ---------------- Haar IDWT (+ll add, crop)
__global__ void idwt_kernel(const float* __restrict__ tl, const float* __restrict__ nxt,
        float* __restrict__ outp, int h2, int w2, int ho, int wo)
{
    int t = blockIdx.x * blockDim.x + threadIdx.x;
    int total = Bc * 32 * ho * wo;
    if (t >= total) return;
    int x = t % wo; int r = t / wo;
    int y = r % ho; r /= ho;
    int c = r & 31; int b = r >> 5;
    int y2 = y >> 1, x2 = x >> 1;
    size_t pl = (size_t)h2 * w2;
    size_t base = (size_t)(b * 128 + c * 4) * pl + y2 * w2 + x2;
    float ll = tl[base];
    if (nxt) ll += nxt[(size_t)(b * 32 + c) * pl + y2 * w2 + x2];
    float lh = tl[base + pl], hl = tl[base + 2 * pl], hh = tl[base + 3 * pl];
    float v;
    if ((y & 1) == 0) v = ((x & 1) == 0) ? (ll - lh - hl + hh) : (ll - lh + hl - hh);
    else              v = ((x & 1) == 0) ? (ll + lh - hl - hh) : (ll + lh + hl + hh);
    outp[t] = v * 0.5f;
}

// ---------------- cp2d weight prep: HWIO (3,3,32,32) fp32 -> Wt[co][k=(u3v)*32+ci] bf16
__global__ void cpwt_kernel(const float* __restrict__ in, bf16* __restrict__ out)
{
    int t = blockIdx.x * blockDim.x + threadIdx.x;
    if (t >= 9216) return;
    int co = t / 288, k = t % 288;
    out[t] = __float2bfloat16(in[k * 32 + co]);
}

// ---------------- cp2d via implicit-GEMM MFMA: src bf16 NHWC, dst fp32 NHWC
// block = (b, 8x8 spatial tile); 256 thr = 4 waves; M=64 pixels, N=32 co, K=288
__global__ __launch_bounds__(256) void cp2d_mfma_kernel(const bf16* __restrict__ src,
        const bf16* __restrict__ wtc, const float* __restrict__ bias,
        float* __restrict__ dst)
{
    __shared__ unsigned short in_s[10 * 400];   // [dy][dx*40 + ci], pad 40
    __shared__ unsigned short w_s[32 * 296];    // [co][k], pad 296
    int tid = threadIdx.x;
    int b = blockIdx.y;
    int ty = blockIdx.x / 7, tx = blockIdx.x % 7;
    for (int idx = tid; idx < 1152; idx += 256) {
        int co = idx / 36, j8 = (idx % 36) * 8;
        *(int4*)&w_s[co * 296 + j8] = *(const int4*)(wtc + co * 288 + j8);
    }
    {
        int idx = tid;
        if (idx < 200) {
            int cell = idx >> 1, half = idx & 1;
            int dy = cell / 10, dx = cell % 10;
            int gy = ty * 8 - 1 + dy, gx = tx * 8 - 1 + dx;
            int4 v0 = make_int4(0, 0, 0, 0), v1 = v0;
            if (gy >= 0 && gy < 56 && gx >= 0 && gx < 56) {
                const int4* gp = (const int4*)(src + ((((size_t)b * 56 + gy) * 56 + gx) * 32 + half * 16));
                v0 = gp[0]; v1 = gp[1];
            }
            *(int4*)&in_s[dy * 400 + dx * 40 + half * 16] = v0;
            *(int4*)&in_s[dy * 400 + dx * 40 + half * 16 + 8] = v1;
        }
    }
    __syncthreads();
    int wave = tid >> 6, lane = tid & 63;
    int ml = lane & 15, qd = lane >> 4;
    int m = wave * 16 + ml;
    int ly = m >> 3, lx = m & 7;
    f32x4 acc0 = {0.f, 0.f, 0.f, 0.f}, acc1 = {0.f, 0.f, 0.f, 0.f};
    #pragma unroll
    for (int u = 0; u < 3; u++)
    #pragma unroll
    for (int v = 0; v < 3; v++) {
        bf16x8 af = *(const bf16x8*)&in_s[(ly + u) * 400 + (lx + v) * 40 + qd * 8];
        int k = (u * 3 + v) * 32 + qd * 8;
        bf16x8 b0 = *(const bf16x8*)&w_s[ml * 296 + k];
        bf16x8 b1 = *(const bf16x8*)&w_s[(16 + ml) * 296 + k];
        acc0 = __builtin_amdgcn_mfma_f32_16x16x32_bf16(af, b0, acc0, 0, 0, 0);
        acc1 = __builtin_amdgcn_mfma_f32_16x16x32_bf16(af, b1, acc1, 0, 0, 0);
    }
    float bia0 = bias[ml], bia1 = bias[16 + ml];
    #pragma unroll
    for (int r = 0; r < 4; r++) {
        int mr = wave * 16 + qd * 4 + r;
        int ry = ty * 8 + (mr >> 3), rx = tx * 8 + (mr & 7);
        float* dp = dst + (((size_t)b * 56 + ry) * 56 + rx) * 32;
        dp[ml] = acc0[r] + bia0;
        dp[16 + ml] = acc1[r] + bia1;
    }
}

// ---------------- cn: LN over 32 ch (NHWC contiguous) + gelu -> bf16 attn_cat cols 96..127
__global__ void cn_kernel(const float* __restrict__ cb, const float* __restrict__ g,
        const float* __restrict__ be, bf16* __restrict__ attn_cat)
{
    int t = blockIdx.x * blockDim.x + threadIdx.x;
    if (t >= Bc * Nc) return;
    const float* p = cb + (size_t)t * 32;
    float v[32]; float s = 0.f;
    #pragma unroll
    for (int c = 0; c < 32; c++) { v[c] = p[c]; s += v[c]; }
    float mean = s * (1.f / 32.f), q = 0.f;
    #pragma unroll
    for (int c = 0; c < 32; c++) { float d = v[c] - mean; q += d * d; }
    float inv = rsqrtf(q * (1.f / 32.f) + EPSc);
    bf16* o = attn_cat + (size_t)t * 128 + 96;
    #pragma unroll
    for (int c = 0; c < 32; c++)
        o[c] = __float2bfloat16(gelu_f((v[c] - mean) * inv * g[c] + be[c]));
}

// ---------------- sr: depthwise ks x ks stride ks VALID; out (B,L,96) fp32
__global__ void sr_kernel(const float* __restrict__ xa, const float* __restrict__ wt,
        const float* __restrict__ bias, float* __restrict__ outp, int ks, int Ld)
{
    int t = blockIdx.x * blockDim.x + threadIdx.x;
    int total = Bc * Ld * Ld * Cac;
    if (t >= total) return;
    int c = t % Cac; int r = t / Cac;
    int j = r % Ld; r /= Ld;
    int i = r % Ld; int b = r / Ld;
    float acc = bias[c];
    for (int u = 0; u < ks; u++)
        for (int v = 0; v < ks; v++)
            acc += xa[(size_t)(b * Nc + (i * ks + u) * Wcc + (j * ks + v)) * Cac + c]
                 * wt[(u * ks + v) * Cac + c];
    outp[t] = acc;
}

// ---------------- LN over 96 + gelu -> bf16
__global__ __launch_bounds__(256) void ln96_kernel(const float* __restrict__ src,
        const float* __restrict__ g, const float* __restrict__ be,
        bf16* __restrict__ dst, int R)
{
    int wv = threadIdx.x >> 6, lane = threadIdx.x & 63;
    int row = blockIdx.x * 4 + wv;
    if (row >= R) return;
    const float* sp = src + (size_t)row * 96;
    float x0 = sp[lane];
    float x1 = (lane < 32) ? sp[64 + lane] : 0.f;
    float s = x0 + x1, q = x0 * x0 + x1 * x1;
    for (int o = 32; o; o >>= 1) { s += __shfl_xor(s, o); q += __shfl_xor(q, o); }
    float mean = s * (1.f / 96.f);
    float inv = rsqrtf(q * (1.f / 96.f) - mean * mean + EPSc);
    dst[(size_t)row * 96 + lane] =
        __float2bfloat16(gelu_f((x0 - mean) * inv * g[lane] + be[lane]));
    if (lane < 32)
        dst[(size_t)row * 96 + 64 + lane] =
            __float2bfloat16(gelu_f((x1 - mean) * inv * g[64 + lane] + be[64 + lane]));
}

// ---------------- LN2: (B,N,128) fp32 -> bf16
__global__ __launch_bounds__(256) void ln2_kernel(const float* __restrict__ xres,
        const float* __restrict__ g, const float* __restrict__ be,
        bf16* __restrict__ xnb)
{
    int wv = threadIdx.x >> 6, lane = threadIdx.x & 63;
    int row = blockIdx.x * 4 + wv;
    if (row >= Bc * Nc) return;
    const float* xr = xres + (size_t)row * 128;
    float x0 = xr[lane], x1 = xr[lane + 64];
    float s = x0 + x1, q = x0 * x0 + x1 * x1;
    for (int o = 32; o; o >>= 1) { s += __shfl_xor(s, o); q += __shfl_xor(q, o); }
    float mean = s * (1.f / 128.f);
    float inv = rsqrtf(q * (1.f / 128.f) - mean * mean + EPSc);
    xnb[(size_t)row * 128 + lane] =
        __float2bfloat16((x0 - mean) * inv * g[lane] + be[lane]);
    xnb[(size_t)row * 128 + lane + 64] =
        __float2bfloat16((x1 - mean) * inv * g[lane + 64] + be[lane + 64]);
}

// ---------------- weight transpose + convert: in (K,N) fp32 -> out (N,K) bf16
__global__ void wtrans_kernel(const float* __restrict__ in, bf16* __restrict__ out,
                              int K, int N)
{
    int t = blockIdx.x * blockDim.x + threadIdx.x;
    if (t >= K * N) return;
    int n = t % N, k = t / N;
    out[(size_t)n * K + k] = __float2bfloat16(in[t]);
}

// ---------------- MFMA GEMM: out(MxNt) = A(MxK bf16) x Wt(NtxK bf16)^T [+bias][gelu][+res fp32]
template<int NF, bool GELU, bool RES, bool OUTBF>
__global__ __launch_bounds__(256) void gemm_kernel(const bf16* __restrict__ A,
        const bf16* __restrict__ Wt, const float* __restrict__ bias,
        const float* __restrict__ res, void* __restrict__ outp,
        int M, int K, int Nt)
{
    constexpr int TN = 16 * NF;
    __shared__ unsigned short As[64][40];
    __shared__ unsigned short Bs[TN][40];
    int tid = threadIdx.x;
    int wave = tid >> 6, lane = tid & 63;
    int m0 = blockIdx.y * 64, n0 = blockIdx.x * TN;
    f32x4 acc[NF];
    #pragma unroll
    for (int f = 0; f < NF; f++) acc[f] = (f32x4){0.f, 0.f, 0.f, 0.f};

    int ar = tid >> 2, ac = (tid & 3) << 3;
    int ml = wave * 16 + (lane & 15);
    int qd = lane >> 4;

    for (int k0 = 0; k0 < K; k0 += 32) {
        int4 av = make_int4(0, 0, 0, 0);
        if (m0 + ar < M) av = *(const int4*)(A + (size_t)(m0 + ar) * K + k0 + ac);
        *(int4*)&As[ar][ac] = av;
        for (int idx = tid; idx < TN * 4; idx += 256) {
            int br = idx >> 2, bc = (idx & 3) << 3;
            *(int4*)&Bs[br][bc] = *(const int4*)(Wt + (size_t)(n0 + br) * K + k0 + bc);
        }
        __syncthreads();
        bf16x8 af = *(const bf16x8*)&As[ml][qd * 8];
        #pragma unroll
        for (int f = 0; f < NF; f++) {
            bf16x8 bfv = *(const bf16x8*)&Bs[f * 16 + (lane & 15)][qd * 8];
            acc[f] = __builtin_amdgcn_mfma_f32_16x16x32_bf16(af, bfv, acc[f], 0, 0, 0);
        }
        __syncthreads();
    }
    #pragma unroll
    for (int f = 0; f < NF; f++) {
        int n = n0 + f * 16 + (lane & 15);
        #pragma unroll
        for (int r = 0; r < 4; r++) {
            int m = m0 + wave * 16 + qd * 4 + r;
            if (m >= M) continue;
            float v = acc[f][r];
            if (bias) v += bias[n];
            if (GELU) v = gelu_f(v);
            if (RES)  v += res[(size_t)m * Nt + n];
            if (OUTBF) ((bf16*)outp)[(size_t)m * Nt + n] = __float2bfloat16(v);
            else       ((float*)outp)[(size_t)m * Nt + n] = v;
        }
    }
}

// ---------------- attention: per (b, head) block; K/V in LDS; writes bf16 attn_cat
__global__ __launch_bounds__(256) void attn_kernel(const float* __restrict__ q,
        const float* __restrict__ kv, bf16* __restrict__ attn_cat,
        int L, int hbase)
{
    __shared__ float kb[196 * 12];
    __shared__ float vb[196 * 12];
    int hl = blockIdx.y, b = blockIdx.z;
    int h = hbase + hl;
    for (int idx = threadIdx.x; idx < L * 12; idx += 256) {
        int l = idx / 12, d = idx % 12;
        const float* kp = kv + (size_t)(b * L + l) * 96 + hl * 12 + d;
        kb[idx] = kp[0];
        vb[idx] = kp[48];
    }
    __syncthreads();
    int n = blockIdx.x * 256 + threadIdx.x;
    if (n >= Nc) return;
    float qr[12];
    const float* qp = q + (size_t)(b * Nc + n) * 96 + h * 12;
    #pragma unroll
    for (int d = 0; d < 12; d++) qr[d] = qp[d];
    float mx = -1e30f;
    for (int l = 0; l < L; l++) {
        float s = 0.f;
        #pragma unroll
        for (int d = 0; d < 12; d++) s += qr[d] * kb[l * 12 + d];
        mx = fmaxf(mx, s);
    }
    float mxs = mx * SCALEc;
    float den = 0.f;
    float o[12];
    #pragma unroll
    for (int d = 0; d < 12; d++) o[d] = 0.f;
    for (int l = 0; l < L; l++) {
        float s = 0.f;
        #pragma unroll
        for (int d = 0; d < 12; d++) s += qr[d] * kb[l * 12 + d];
        float e = __expf(s * SCALEc - mxs);
        den += e;
        #pragma unroll
        for (int d = 0; d < 12; d++) o[d] += e * vb[l * 12 + d];
    }
    float rden = 1.f / den;
    bf16* op = attn_cat + (size_t)(b * Nc + n) * 128 + h * 12;
    #pragma unroll
    for (int d = 0; d < 12; d++) op[d] = __float2bfloat16(o[d] * rden);
}

extern "C" void kernel_launch(void* const* d_in, const int* in_sizes, int n_in,
                              void* d_out, int out_size, void* d_ws, size_t ws_size,
                              hipStream_t stream)
{
    const float* x    = (const float*)d_in[0];
    const float* ln1w = (const float*)d_in[3];
    const float* ln1b = (const float*)d_in[4];
    const float* ln2w = (const float*)d_in[5];
    const float* ln2b = (const float*)d_in[6];
    const float* qw   = (const float*)d_in[7];
    const float* kv1w = (const float*)d_in[8];
    const float* kv2w = (const float*)d_in[9];
    const float* sr1w = (const float*)d_in[10];
    const float* sr1b = (const float*)d_in[11];
    const float* sr2w = (const float*)d_in[12];
    const float* sr2b = (const float*)d_in[13];
    const float* an1w = (const float*)d_in[14];
    const float* an1b = (const float*)d_in[15];
    const float* an2w = (const float*)d_in[16];
    const float* an2b = (const float*)d_in[17];
    const float* wbw  = (const float*)d_in[18];
    const float* wbb  = (const float*)d_in[19];
    const float* wbs  = (const float*)d_in[20];
    const float* wavw = (const float*)d_in[21];
    const float* wavs = (const float*)d_in[22];
    const float* cpw  = (const float*)d_in[23];
    const float* cpb  = (const float*)d_in[24];
    const float* cnw  = (const float*)d_in[25];
    const float* cnb  = (const float*)d_in[26];
    const float* pw   = (const float*)d_in[27];
    const float* pb   = (const float*)d_in[28];
    const float* f1w  = (const float*)d_in[29];
    const float* f1b  = (const float*)d_in[30];
    const float* f2w  = (const float*)d_in[31];
    const float* f2b  = (const float*)d_in[32];
    float* dout = (float*)d_out;
    float* ws = (float*)d_ws;

    // workspace layout (float offsets; all 16B-aligned)
    float* XA    = ws;                      // 9,633,792
    float* QB    = ws + 9633792;            // -> 19,267,584
    float* XRES  = ws;                      // overlay (XA+QB head; dead by proj)
    bf16*  XNb   = (bf16*)(ws + 12845056);  // bf16, QB tail overlay (dead by ln2)
    bf16*  XAb   = (bf16*)(ws + 19267584);  // 9,633,792 bf16
    bf16*  ACATb = (bf16*)(ws + 24084480);  // 12,845,056 bf16
    float* XCI   = ws + 30507008;           // 3,211,264
    float* SUB   = ws + 33718272;           // 4,296,704
    float* TT    = ws + 38014976;           // 4,296,704
    float* RA    = ws + 42311680;           // 3,211,264
    float* RB    = ws + 45522944;           // 3,211,264
    float* X1P   = ws + 48734208;           // 150,528
    float* X2P   = ws + 48884736;           // 602,112
    bf16*  X1Bb  = (bf16*)(ws + 49486848);  // 150,528 bf16
    bf16*  X2Bb  = (bf16*)(ws + 49562112);  // 602,112 bf16
    float* KV1   = ws + 49863168;           // 150,528
    float* KV2   = ws + 50013696;           // 602,112
    bf16*  WTB   = (bf16*)(ws + 50615808);  // weights bf16
    bf16*  qwt   = WTB;
    bf16*  kv1wt = WTB + 9216;
    bf16*  kv2wt = WTB + 18432;
    bf16*  pwt   = WTB + 27648;
    bf16*  w1t   = WTB + 44032;
    bf16*  w2t   = WTB + 109568;
    bf16*  cpwt  = WTB + 175104;            // 9216 -> WTB total 184,320 bf16
    bf16*  Hb    = (bf16*)(ws + 24084480);  // hidden bf16 overlay (dead regions by fc1)
    // WT path overlays:
    bf16*  CIMGb = (bf16*)SUB;              // bf16 NHWC (B,56,56,32); SUB dead post-wavelet-convs
    float* CBUF  = TT;                      // fp32 NHWC; TT dead post-idwt-0
    float* S0 = SUB;            float* T0 = TT;
    float* S1 = SUB + 3211264;  float* T1 = TT + 3211264;
    float* S2 = SUB + 4014080;  float* T2 = TT + 4014080;
    float* S3 = SUB + 4214784;  float* T3 = TT + 4214784;
    float* S4 = SUB + 4280320;  float* T4 = TT + 4280320;

    // 0. weight preps (fp32 -> bf16, N-major)
    wtrans_kernel<<<36,  256, 0, stream>>>(qw,   qwt,   96, 96);
    wtrans_kernel<<<36,  256, 0, stream>>>(kv1w, kv1wt, 96, 96);
    wtrans_kernel<<<36,  256, 0, stream>>>(kv2w, kv2wt, 96, 96);
    wtrans_kernel<<<64,  256, 0, stream>>>(pw,   pwt,   128, 128);
    wtrans_kernel<<<256, 256, 0, stream>>>(f1w,  w1t,   128, 512);
    wtrans_kernel<<<256, 256, 0, stream>>>(f2w,  w2t,   512, 128);
    cpwt_kernel<<<36, 256, 0, stream>>>(cpw, cpwt);

    // 1. LN1
    ln1_kernel<<<25088, 256, 0, stream>>>(x, ln1w, ln1b, XA, XAb, XCI);

    // 2. DWT cascade
    dwt_kernel<<<3136, 256, 0, stream>>>(XCI, 1, 56, 56, 28, 28, S0);
    dwt_kernel<<<784,  256, 0, stream>>>(S0, 4, 28, 28, 14, 14, S1);
    dwt_kernel<<<196,  256, 0, stream>>>(S1, 4, 14, 14, 7, 7,   S2);
    dwt_kernel<<<64,   256, 0, stream>>>(S2, 4, 7, 7,   4, 4,   S3);
    dwt_kernel<<<16,   256, 0, stream>>>(S3, 4, 4, 4,   2, 2,   S4);

    // 3. wavelet depthwise convs
    dw3x3_kernel<<<12544, 256, 0, stream>>>(S0, wavw,        wavs,       nullptr, nullptr, T0, 128, 28, 28);
    dw3x3_kernel<<<3136,  256, 0, stream>>>(S1, wavw + 1152, wavs + 128, nullptr, nullptr, T1, 128, 14, 14);
    dw3x3_kernel<<<784,   256, 0, stream>>>(S2, wavw + 2304, wavs + 256, nullptr, nullptr, T2, 128, 7, 7);
    dw3x3_kernel<<<256,   256, 0, stream>>>(S3, wavw + 3456, wavs + 384, nullptr, nullptr, T3, 128, 4, 4);
    dw3x3_kernel<<<64,    256, 0, stream>>>(S4, wavw + 4608, wavs + 512, nullptr, nullptr, T4, 128, 2, 2);

    // 4. IDWT cascade
    idwt_kernel<<<64,    256, 0, stream>>>(T4, nullptr, RA, 2, 2, 4, 4);
    idwt_kernel<<<196,   256, 0, stream>>>(T3, RA, RB, 4, 4, 7, 7);
    idwt_kernel<<<784,   256, 0, stream>>>(T2, RB, RA, 7, 7, 14, 14);
    idwt_kernel<<<3136,  256, 0, stream>>>(T1, RA, RB, 14, 14, 28, 28);
    idwt_kernel<<<12544, 256, 0, stream>>>(T0, RB, RA, 28, 28, 56, 56);

    // 5. base depthwise conv -> bf16 NHWC
    dwbase_kernel<<<12544, 256, 0, stream>>>(XCI, wbw, wbs, wbb, RA, CIMGb);

    // 6. cp2d implicit-GEMM MFMA -> CBUF fp32 NHWC
    cp2d_mfma_kernel<<<dim3(49, 32), 256, 0, stream>>>(CIMGb, cpwt, cpb, CBUF);

    // 7. cn (NHWC) -> ACATb[96:128]
    cn_kernel<<<392, 256, 0, stream>>>(CBUF, cnw, cnb, ACATb);

    // 8/9. spatial reductions
    sr_kernel<<<588,  256, 0, stream>>>(XA, sr1w, sr1b, X1P, 8, 7);
    sr_kernel<<<2352, 256, 0, stream>>>(XA, sr2w, sr2b, X2P, 4, 14);

    // 10. LN96 + gelu -> bf16
    ln96_kernel<<<392,  256, 0, stream>>>(X1P, an1w, an1b, X1Bb, 1568);
    ln96_kernel<<<1568, 256, 0, stream>>>(X2P, an2w, an2b, X2Bb, 6272);

    // 11. q / kv GEMMs (MFMA)
    gemm_kernel<6,false,false,false><<<dim3(1, 1568), 256, 0, stream>>>(XAb,  qwt,   nullptr, nullptr, QB,  100352, 96, 96);
    gemm_kernel<6,false,false,false><<<dim3(1, 25),   256, 0, stream>>>(X1Bb, kv1wt, nullptr, nullptr, KV1, 1568,   96, 96);
    gemm_kernel<6,false,false,false><<<dim3(1, 98),   256, 0, stream>>>(X2Bb, kv2wt, nullptr, nullptr, KV2, 6272,   96, 96);

    // 12. attention -> ACATb[0:96]
    attn_kernel<<<dim3(13, 4, 32), 256, 0, stream>>>(QB, KV1, ACATb, 49, 0);
    attn_kernel<<<dim3(13, 4, 32), 256, 0, stream>>>(QB, KV2, ACATb, 196, 4);

    // 13. proj + bias + residual(x) -> XRES fp32
    gemm_kernel<4,false,true,false><<<dim3(2, 1568), 256, 0, stream>>>(ACATb, pwt, pb, x, XRES, 100352, 128, 128);

    // 14. LN2 -> bf16
    ln2_kernel<<<25088, 256, 0, stream>>>(XRES, ln2w, ln2b, XNb);

    // 15. fc1 + bias + gelu -> Hb bf16
    gemm_kernel<4,true,false,true><<<dim3(8, 1568), 256, 0, stream>>>(XNb, w1t, f1b, nullptr, Hb, 100352, 128, 512);

    // 16. fc2 + bias + residual(XRES) -> d_out fp32
    gemm_kernel<4,false,true,false><<<dim3(2, 1568), 256, 0, stream>>>(Hb, w2t, f2b, XRES, dout, 100352, 512, 128);
}

// Round 5
// 760.985 us; speedup vs baseline: 2.0715x; 1.0168x over previous
//
#include <hip/hip_runtime.h>
#include <hip/hip_bf16.h>
#include <math.h>

typedef __hip_bfloat16 bf16;
typedef __attribute__((ext_vector_type(8))) short bf16x8;
typedef __attribute__((ext_vector_type(4))) float f32x4;

#define Bc   32
#define Hc   56
#define Wcc  56
#define Nc   3136
#define Cpc  32
#define Cac  96
#define EPSc 1e-5f
#define SCALEc 0.28867513459481287f   /* 1/sqrt(12) */

__device__ __forceinline__ float gelu_f(float x) {
    return 0.5f * x * (1.0f + erff(x * 0.7071067811865475f));
}

// ---------------- LN1: (B,N,128) -> xa fp32 (B,N,96) + xab bf16 + xc_img (B,32,56,56) fp32
__global__ __launch_bounds__(256) void ln1_kernel(const float* __restrict__ x,
        const float* __restrict__ g, const float* __restrict__ be,
        float* __restrict__ xa, bf16* __restrict__ xab, float* __restrict__ xc_img)
{
    int wv = threadIdx.x >> 6, lane = threadIdx.x & 63;
    int row = blockIdx.x * 4 + wv;
    if (row >= Bc * Nc) return;
    const float* xr = x + (size_t)row * 128;
    float x0 = xr[lane];
    float x1 = xr[lane + 64];
    float s = x0 + x1, q = x0 * x0 + x1 * x1;
    for (int o = 32; o; o >>= 1) { s += __shfl_xor(s, o); q += __shfl_xor(q, o); }
    float mean = s * (1.f / 128.f);
    float inv = rsqrtf(q * (1.f / 128.f) - mean * mean + EPSc);
    int b = row / Nc, n = row % Nc;
    {
        int c = lane;
        float y = (x0 - mean) * inv * g[c] + be[c];
        if (c < Cpc) xc_img[(size_t)(b * Cpc + c) * Nc + n] = y;
        else { xa[(size_t)row * Cac + (c - Cpc)] = y;
               xab[(size_t)row * Cac + (c - Cpc)] = __float2bfloat16(y); }
    }
    {
        int c = lane + 64;
        float y = (x1 - mean) * inv * g[c] + be[c];
        xa[(size_t)row * Cac + (c - Cpc)] = y;
        xab[(size_t)row * Cac + (c - Cpc)] = __float2bfloat16(y);
    }
}

// ---------------- Haar DWT
__global__ void dwt_kernel(const float* __restrict__ src, int cs, int h, int w,
                           int h2, int w2, float* __restrict__ sub)
{
    int t = blockIdx.x * blockDim.x + threadIdx.x;
    int total = Bc * 32 * h2 * w2;
    if (t >= total) return;
    int xx = t % w2; int r = t / w2;
    int yy = r % h2; r /= h2;
    int c = r & 31; int b = r >> 5;
    const float* sp = src + (size_t)cs * (b * 32 + c) * h * w;
    int y0 = yy * 2, x0 = xx * 2;
    bool xe = (x0 + 1 < w), ye = (y0 + 1 < h);
    float a  = sp[y0 * w + x0];
    float bb = xe ? sp[y0 * w + x0 + 1] : 0.f;
    float cc = ye ? sp[(y0 + 1) * w + x0] : 0.f;
    float dd = (xe && ye) ? sp[(y0 + 1) * w + x0 + 1] : 0.f;
    size_t pl = (size_t)h2 * w2;
    size_t ob = (size_t)(b * 128 + c * 4) * pl + yy * w2 + xx;
    sub[ob]          = ( a + bb + cc + dd) * 0.5f;
    sub[ob + pl]     = (-a - bb + cc + dd) * 0.5f;
    sub[ob + 2 * pl] = (-a + bb - cc + dd) * 0.5f;
    sub[ob + 3 * pl] = ( a - bb - cc + dd) * 0.5f;
}

// ---------------- depthwise 3x3 SAME (generic, fp32 out)
__global__ void dw3x3_kernel(const float* __restrict__ src, const float* __restrict__ wt,
        const float* __restrict__ scale, const float* __restrict__ bias,
        const float* __restrict__ addb, float* __restrict__ dst,
        int C, int h, int w)
{
    int t = blockIdx.x * blockDim.x + threadIdx.x;
    int total = Bc * C * h * w;
    if (t >= total) return;
    int x = t % w; int r = t / w;
    int y = r % h; r /= h;
    int c = r % C;
    const float* sp = src + (size_t)(t - x - y * w);
    float acc = 0.f;
    #pragma unroll
    for (int u = 0; u < 3; u++) {
        int yy = y + u - 1;
        if (yy < 0 || yy >= h) continue;
        #pragma unroll
        for (int v = 0; v < 3; v++) {
            int xx = x + v - 1;
            if (xx < 0 || xx >= w) continue;
            acc += sp[yy * w + xx] * wt[(u * 3 + v) * C + c];
        }
    }
    if (bias) acc += bias[c];
    acc *= scale[c];
    if (addb) acc += addb[t];
    dst[t] = acc;
}

// ---------------- base depthwise 3x3 + bias, *scale, +recon -> bf16 NHWC (B,56,56,32)
__global__ void dwbase_kernel(const float* __restrict__ src, const float* __restrict__ wt,
        const float* __restrict__ scale, const float* __restrict__ bias,
        const float* __restrict__ addb, bf16* __restrict__ dst_nhwc)
{
    int t = blockIdx.x * blockDim.x + threadIdx.x;
    int total = Bc * 32 * Nc;
    if (t >= total) return;
    int x = t % Wcc; int r = t / Wcc;
    int y = r % Hc; r /= Hc;
    int c = r & 31; int b = r >> 5;
    const float* sp = src + (size_t)(t - x - y * Wcc);
    float acc = 0.f;
    #pragma unroll
    for (int u = 0; u < 3; u++) {
        int yy = y + u - 1;
        if (yy < 0 || yy >= Hc) continue;
        #pragma unroll
        for (int v = 0; v < 3; v++) {
            int xx = x + v - 1;
            if (xx < 0 || xx >= Wcc) continue;
            acc += sp[yy * Wcc + xx] * wt[(u * 3 + v) * 32 + c];
        }
    }
    acc = (acc + bias[c]) * scale[c] + addb[t];
    dst_nhwc[(((size_t)b * Hc + y) * Wcc + x) * 32 + c] = __float2bfloat16(acc);
}

// ---------------- Haar IDWT (+ll add, crop)
__global__ void idwt_kernel(const float* __restrict__ tl, const float* __restrict__ nxt,
        float* __restrict__ outp, int h2, int w2, int ho, int wo)
{
    int t = blockIdx.x * blockDim.x + threadIdx.x;
    int total = Bc * 32 * ho * wo;
    if (t >= total) return;
    int x = t % wo; int r = t / wo;
    int y = r % ho; r /= ho;
    int c = r & 31; int b = r >> 5;
    int y2 = y >> 1, x2 = x >> 1;
    size_t pl = (size_t)h2 * w2;
    size_t base = (size_t)(b * 128 + c * 4) * pl + y2 * w2 + x2;
    float ll = tl[base];
    if (nxt) ll += nxt[(size_t)(b * 32 + c) * pl + y2 * w2 + x2];
    float lh = tl[base + pl], hl = tl[base + 2 * pl], hh = tl[base + 3 * pl];
    float v;
    if ((y & 1) == 0) v = ((x & 1) == 0) ? (ll - lh - hl + hh) : (ll - lh + hl - hh);
    else              v = ((x & 1) == 0) ? (ll + lh - hl - hh) : (ll + lh + hl + hh);
    outp[t] = v * 0.5f;
}

// ---------------- cp2d weight prep: HWIO (3,3,32,32) fp32 -> Wt[co][k=(u3v)*32+ci] bf16
__global__ void cpwt_kernel(const float* __restrict__ in, bf16* __restrict__ out)
{
    int t = blockIdx.x * blockDim.x + threadIdx.x;
    if (t >= 9216) return;
    int co = t / 288, k = t % 288;
    out[t] = __float2bfloat16(in[k * 32 + co]);
}

// ---------------- cp2d via implicit-GEMM MFMA: src bf16 NHWC, dst fp32 NHWC
__global__ __launch_bounds__(256) void cp2d_mfma_kernel(const bf16* __restrict__ src,
        const bf16* __restrict__ wtc, const float* __restrict__ bias,
        float* __restrict__ dst)
{
    __shared__ unsigned short in_s[10 * 400];
    __shared__ unsigned short w_s[32 * 296];
    int tid = threadIdx.x;
    int b = blockIdx.y;
    int ty = blockIdx.x / 7, tx = blockIdx.x % 7;
    for (int idx = tid; idx < 1152; idx += 256) {
        int co = idx / 36, j8 = (idx % 36) * 8;
        *(int4*)&w_s[co * 296 + j8] = *(const int4*)(wtc + co * 288 + j8);
    }
    {
        int idx = tid;
        if (idx < 200) {
            int cell = idx >> 1, half = idx & 1;
            int dy = cell / 10, dx = cell % 10;
            int gy = ty * 8 - 1 + dy, gx = tx * 8 - 1 + dx;
            int4 v0 = make_int4(0, 0, 0, 0), v1 = v0;
            if (gy >= 0 && gy < 56 && gx >= 0 && gx < 56) {
                const int4* gp = (const int4*)(src + ((((size_t)b * 56 + gy) * 56 + gx) * 32 + half * 16));
                v0 = gp[0]; v1 = gp[1];
            }
            *(int4*)&in_s[dy * 400 + dx * 40 + half * 16] = v0;
            *(int4*)&in_s[dy * 400 + dx * 40 + half * 16 + 8] = v1;
        }
    }
    __syncthreads();
    int wave = tid >> 6, lane = tid & 63;
    int ml = lane & 15, qd = lane >> 4;
    int m = wave * 16 + ml;
    int ly = m >> 3, lx = m & 7;
    f32x4 acc0 = {0.f, 0.f, 0.f, 0.f}, acc1 = {0.f, 0.f, 0.f, 0.f};
    #pragma unroll
    for (int u = 0; u < 3; u++)
    #pragma unroll
    for (int v = 0; v < 3; v++) {
        bf16x8 af = *(const bf16x8*)&in_s[(ly + u) * 400 + (lx + v) * 40 + qd * 8];
        int k = (u * 3 + v) * 32 + qd * 8;
        bf16x8 b0 = *(const bf16x8*)&w_s[ml * 296 + k];
        bf16x8 b1 = *(const bf16x8*)&w_s[(16 + ml) * 296 + k];
        acc0 = __builtin_amdgcn_mfma_f32_16x16x32_bf16(af, b0, acc0, 0, 0, 0);
        acc1 = __builtin_amdgcn_mfma_f32_16x16x32_bf16(af, b1, acc1, 0, 0, 0);
    }
    float bia0 = bias[ml], bia1 = bias[16 + ml];
    #pragma unroll
    for (int r = 0; r < 4; r++) {
        int mr = wave * 16 + qd * 4 + r;
        int ry = ty * 8 + (mr >> 3), rx = tx * 8 + (mr & 7);
        float* dp = dst + (((size_t)b * 56 + ry) * 56 + rx) * 32;
        dp[ml] = acc0[r] + bia0;
        dp[16 + ml] = acc1[r] + bia1;
    }
}

// ---------------- cn: LN over 32 ch (NHWC contiguous) + gelu -> bf16 attn_cat cols 96..127
__global__ void cn_kernel(const float* __restrict__ cb, const float* __restrict__ g,
        const float* __restrict__ be, bf16* __restrict__ attn_cat)
{
    int t = blockIdx.x * blockDim.x + threadIdx.x;
    if (t >= Bc * Nc) return;
    const float* p = cb + (size_t)t * 32;
    float v[32]; float s = 0.f;
    #pragma unroll
    for (int c = 0; c < 32; c++) { v[c] = p[c]; s += v[c]; }
    float mean = s * (1.f / 32.f), q = 0.f;
    #pragma unroll
    for (int c = 0; c < 32; c++) { float d = v[c] - mean; q += d * d; }
    float inv = rsqrtf(q * (1.f / 32.f) + EPSc);
    bf16* o = attn_cat + (size_t)t * 128 + 96;
    #pragma unroll
    for (int c = 0; c < 32; c++)
        o[c] = __float2bfloat16(gelu_f((v[c] - mean) * inv * g[c] + be[c]));
}

// ---------------- sr: depthwise ks x ks stride ks VALID; out (B,L,96) fp32
__global__ void sr_kernel(const float* __restrict__ xa, const float* __restrict__ wt,
        const float* __restrict__ bias, float* __restrict__ outp, int ks, int Ld)
{
    int t = blockIdx.x * blockDim.x + threadIdx.x;
    int total = Bc * Ld * Ld * Cac;
    if (t >= total) return;
    int c = t % Cac; int r = t / Cac;
    int j = r % Ld; r /= Ld;
    int i = r % Ld; int b = r / Ld;
    float acc = bias[c];
    for (int u = 0; u < ks; u++)
        for (int v = 0; v < ks; v++)
            acc += xa[(size_t)(b * Nc + (i * ks + u) * Wcc + (j * ks + v)) * Cac + c]
                 * wt[(u * ks + v) * Cac + c];
    outp[t] = acc;
}

// ---------------- LN over 96 + gelu -> bf16
__global__ __launch_bounds__(256) void ln96_kernel(const float* __restrict__ src,
        const float* __restrict__ g, const float* __restrict__ be,
        bf16* __restrict__ dst, int R)
{
    int wv = threadIdx.x >> 6, lane = threadIdx.x & 63;
    int row = blockIdx.x * 4 + wv;
    if (row >= R) return;
    const float* sp = src + (size_t)row * 96;
    float x0 = sp[lane];
    float x1 = (lane < 32) ? sp[64 + lane] : 0.f;
    float s = x0 + x1, q = x0 * x0 + x1 * x1;
    for (int o = 32; o; o >>= 1) { s += __shfl_xor(s, o); q += __shfl_xor(q, o); }
    float mean = s * (1.f / 96.f);
    float inv = rsqrtf(q * (1.f / 96.f) - mean * mean + EPSc);
    dst[(size_t)row * 96 + lane] =
        __float2bfloat16(gelu_f((x0 - mean) * inv * g[lane] + be[lane]));
    if (lane < 32)
        dst[(size_t)row * 96 + 64 + lane] =
            __float2bfloat16(gelu_f((x1 - mean) * inv * g[64 + lane] + be[64 + lane]));
}

// ---------------- LN2: (B,N,128) fp32 -> bf16
__global__ __launch_bounds__(256) void ln2_kernel(const float* __restrict__ xres,
        const float* __restrict__ g, const float* __restrict__ be,
        bf16* __restrict__ xnb)
{
    int wv = threadIdx.x >> 6, lane = threadIdx.x & 63;
    int row = blockIdx.x * 4 + wv;
    if (row >= Bc * Nc) return;
    const float* xr = xres + (size_t)row * 128;
    float x0 = xr[lane], x1 = xr[lane + 64];
    float s = x0 + x1, q = x0 * x0 + x1 * x1;
    for (int o = 32; o; o >>= 1) { s += __shfl_xor(s, o); q += __shfl_xor(q, o); }
    float mean = s * (1.f / 128.f);
    float inv = rsqrtf(q * (1.f / 128.f) - mean * mean + EPSc);
    xnb[(size_t)row * 128 + lane] =
        __float2bfloat16((x0 - mean) * inv * g[lane] + be[lane]);
    xnb[(size_t)row * 128 + lane + 64] =
        __float2bfloat16((x1 - mean) * inv * g[lane + 64] + be[lane + 64]);
}

// ---------------- weight transpose + convert: in (K,N) fp32 -> out (N,K) bf16
__global__ void wtrans_kernel(const float* __restrict__ in, bf16* __restrict__ out,
                              int K, int N)
{
    int t = blockIdx.x * blockDim.x + threadIdx.x;
    if (t >= K * N) return;
    int n = t % N, k = t / N;
    out[(size_t)n * K + k] = __float2bfloat16(in[t]);
}

// ---------------- MFMA GEMM. OMODE: 0 = fp32 row-major, 1 = bf16 row-major,
// 2 = fp32 head-major Q layout (B,8,N,12) from Nt=96 cols
template<int NF, bool GELU, bool RES, int OMODE>
__global__ __launch_bounds__(256) void gemm_kernel(const bf16* __restrict__ A,
        const bf16* __restrict__ Wt, const float* __restrict__ bias,
        const float* __restrict__ res, void* __restrict__ outp,
        int M, int K, int Nt)
{
    constexpr int TN = 16 * NF;
    __shared__ unsigned short As[64][40];
    __shared__ unsigned short Bs[TN][40];
    int tid = threadIdx.x;
    int wave = tid >> 6, lane = tid & 63;
    int m0 = blockIdx.y * 64, n0 = blockIdx.x * TN;
    f32x4 acc[NF];
    #pragma unroll
    for (int f = 0; f < NF; f++) acc[f] = (f32x4){0.f, 0.f, 0.f, 0.f};

    int ar = tid >> 2, ac = (tid & 3) << 3;
    int ml = wave * 16 + (lane & 15);
    int qd = lane >> 4;

    for (int k0 = 0; k0 < K; k0 += 32) {
        int4 av = make_int4(0, 0, 0, 0);
        if (m0 + ar < M) av = *(const int4*)(A + (size_t)(m0 + ar) * K + k0 + ac);
        *(int4*)&As[ar][ac] = av;
        for (int idx = tid; idx < TN * 4; idx += 256) {
            int br = idx >> 2, bc = (idx & 3) << 3;
            *(int4*)&Bs[br][bc] = *(const int4*)(Wt + (size_t)(n0 + br) * K + k0 + bc);
        }
        __syncthreads();
        bf16x8 af = *(const bf16x8*)&As[ml][qd * 8];
        #pragma unroll
        for (int f = 0; f < NF; f++) {
            bf16x8 bfv = *(const bf16x8*)&Bs[f * 16 + (lane & 15)][qd * 8];
            acc[f] = __builtin_amdgcn_mfma_f32_16x16x32_bf16(af, bfv, acc[f], 0, 0, 0);
        }
        __syncthreads();
    }
    #pragma unroll
    for (int f = 0; f < NF; f++) {
        int n = n0 + f * 16 + (lane & 15);
        #pragma unroll
        for (int r = 0; r < 4; r++) {
            int m = m0 + wave * 16 + qd * 4 + r;
            if (m >= M) continue;
            float v = acc[f][r];
            if (bias) v += bias[n];
            if (GELU) v = gelu_f(v);
            if (RES)  v += res[(size_t)m * Nt + n];
            if (OMODE == 1)
                ((bf16*)outp)[(size_t)m * Nt + n] = __float2bfloat16(v);
            else if (OMODE == 2) {
                int b = m / Nc, nn = m - b * Nc;
                int h = n / 12, d = n - h * 12;
                ((float*)outp)[(((size_t)(b * 8 + h)) * Nc + nn) * 12 + d] = v;
            } else
                ((float*)outp)[(size_t)m * Nt + n] = v;
        }
    }
}

// ---------------- attention (both branches merged): q head-major (B,8,N,12);
// online softmax single pass; writes bf16 attn_cat[0:96]
__global__ __launch_bounds__(256) void attn_kernel(const float* __restrict__ qh,
        const float* __restrict__ kv1, const float* __restrict__ kv2,
        bf16* __restrict__ attn_cat)
{
    __shared__ float kb[196 * 12];
    __shared__ float vb[196 * 12];
    int h = blockIdx.y, b = blockIdx.z;
    const float* kv; int L, hl;
    if (h < 4) { kv = kv1; L = 49;  hl = h; }
    else       { kv = kv2; L = 196; hl = h - 4; }
    for (int idx = threadIdx.x; idx < L * 12; idx += 256) {
        int l = idx / 12, d = idx % 12;
        const float* kp = kv + (size_t)(b * L + l) * 96 + hl * 12 + d;
        kb[idx] = kp[0];
        vb[idx] = kp[48];
    }
    __syncthreads();
    int n = blockIdx.x * 256 + threadIdx.x;
    if (n >= Nc) return;
    float qr[12];
    const float4* qp = (const float4*)(qh + (((size_t)(b * 8 + h)) * Nc + n) * 12);
    float4 q0 = qp[0], q1 = qp[1], q2 = qp[2];
    qr[0]=q0.x; qr[1]=q0.y; qr[2]=q0.z; qr[3]=q0.w;
    qr[4]=q1.x; qr[5]=q1.y; qr[6]=q1.z; qr[7]=q1.w;
    qr[8]=q2.x; qr[9]=q2.y; qr[10]=q2.z; qr[11]=q2.w;
    #pragma unroll
    for (int d = 0; d < 12; d++) qr[d] *= SCALEc;
    float mx = -1e30f, den = 0.f;
    float o[12];
    #pragma unroll
    for (int d = 0; d < 12; d++) o[d] = 0.f;
    for (int l = 0; l < L; l++) {
        float s = 0.f;
        #pragma unroll
        for (int d = 0; d < 12; d++) s += qr[d] * kb[l * 12 + d];
        if (s > mx) {
            float corr = __expf(mx - s);
            den *= corr;
            #pragma unroll
            for (int d = 0; d < 12; d++) o[d] *= corr;
            mx = s;
        }
        float e = __expf(s - mx);
        den += e;
        #pragma unroll
        for (int d = 0; d < 12; d++) o[d] += e * vb[l * 12 + d];
    }
    float rden = 1.f / den;
    bf16* op = attn_cat + (size_t)(b * Nc + n) * 128 + h * 12;
    #pragma unroll
    for (int d = 0; d < 12; d++) op[d] = __float2bfloat16(o[d] * rden);
}

extern "C" void kernel_launch(void* const* d_in, const int* in_sizes, int n_in,
                              void* d_out, int out_size, void* d_ws, size_t ws_size,
                              hipStream_t stream)
{
    const float* x    = (const float*)d_in[0];
    const float* ln1w = (const float*)d_in[3];
    const float* ln1b = (const float*)d_in[4];
    const float* ln2w = (const float*)d_in[5];
    const float* ln2b = (const float*)d_in[6];
    const float* qw   = (const float*)d_in[7];
    const float* kv1w = (const float*)d_in[8];
    const float* kv2w = (const float*)d_in[9];
    const float* sr1w = (const float*)d_in[10];
    const float* sr1b = (const float*)d_in[11];
    const float* sr2w = (const float*)d_in[12];
    const float* sr2b = (const float*)d_in[13];
    const float* an1w = (const float*)d_in[14];
    const float* an1b = (const float*)d_in[15];
    const float* an2w = (const float*)d_in[16];
    const float* an2b = (const float*)d_in[17];
    const float* wbw  = (const float*)d_in[18];
    const float* wbb  = (const float*)d_in[19];
    const float* wbs  = (const float*)d_in[20];
    const float* wavw = (const float*)d_in[21];
    const float* wavs = (const float*)d_in[22];
    const float* cpw  = (const float*)d_in[23];
    const float* cpb  = (const float*)d_in[24];
    const float* cnw  = (const float*)d_in[25];
    const float* cnb  = (const float*)d_in[26];
    const float* pw   = (const float*)d_in[27];
    const float* pb   = (const float*)d_in[28];
    const float* f1w  = (const float*)d_in[29];
    const float* f1b  = (const float*)d_in[30];
    const float* f2w  = (const float*)d_in[31];
    const float* f2b  = (const float*)d_in[32];
    float* dout = (float*)d_out;
    float* ws = (float*)d_ws;

    float* XA    = ws;                      // 9,633,792
    float* QB    = ws + 9633792;            // head-major Q (B,8,N,12)
    float* XRES  = ws;                      // overlay
    bf16*  XNb   = (bf16*)(ws + 12845056);
    bf16*  XAb   = (bf16*)(ws + 19267584);
    bf16*  ACATb = (bf16*)(ws + 24084480);
    float* XCI   = ws + 30507008;
    float* SUB   = ws + 33718272;
    float* TT    = ws + 38014976;
    float* RA    = ws + 42311680;
    float* RB    = ws + 45522944;
    float* X1P   = ws + 48734208;
    float* X2P   = ws + 48884736;
    bf16*  X1Bb  = (bf16*)(ws + 49486848);
    bf16*  X2Bb  = (bf16*)(ws + 49562112);
    float* KV1   = ws + 49863168;
    float* KV2   = ws + 50013696;
    bf16*  WTB   = (bf16*)(ws + 50615808);
    bf16*  qwt   = WTB;
    bf16*  kv1wt = WTB + 9216;
    bf16*  kv2wt = WTB + 18432;
    bf16*  pwt   = WTB + 27648;
    bf16*  w1t   = WTB + 44032;
    bf16*  w2t   = WTB + 109568;
    bf16*  cpwt  = WTB + 175104;
    bf16*  Hb    = (bf16*)(ws + 24084480);
    bf16*  CIMGb = (bf16*)SUB;
    float* CBUF  = TT;
    float* S0 = SUB;            float* T0 = TT;
    float* S1 = SUB + 3211264;  float* T1 = TT + 3211264;
    float* S2 = SUB + 4014080;  float* T2 = TT + 4014080;
    float* S3 = SUB + 4214784;  float* T3 = TT + 4214784;
    float* S4 = SUB + 4280320;  float* T4 = TT + 4280320;

    // 0. weight preps
    wtrans_kernel<<<36,  256, 0, stream>>>(qw,   qwt,   96, 96);
    wtrans_kernel<<<36,  256, 0, stream>>>(kv1w, kv1wt, 96, 96);
    wtrans_kernel<<<36,  256, 0, stream>>>(kv2w, kv2wt, 96, 96);
    wtrans_kernel<<<64,  256, 0, stream>>>(pw,   pwt,   128, 128);
    wtrans_kernel<<<256, 256, 0, stream>>>(f1w,  w1t,   128, 512);
    wtrans_kernel<<<256, 256, 0, stream>>>(f2w,  w2t,   512, 128);
    cpwt_kernel<<<36, 256, 0, stream>>>(cpw, cpwt);

    // 1. LN1
    ln1_kernel<<<25088, 256, 0, stream>>>(x, ln1w, ln1b, XA, XAb, XCI);

    // 2. DWT cascade
    dwt_kernel<<<3136, 256, 0, stream>>>(XCI, 1, 56, 56, 28, 28, S0);
    dwt_kernel<<<784,  256, 0, stream>>>(S0, 4, 28, 28, 14, 14, S1);
    dwt_kernel<<<196,  256, 0, stream>>>(S1, 4, 14, 14, 7, 7,   S2);
    dwt_kernel<<<64,   256, 0, stream>>>(S2, 4, 7, 7,   4, 4,   S3);
    dwt_kernel<<<16,   256, 0, stream>>>(S3, 4, 4, 4,   2, 2,   S4);

    // 3. wavelet depthwise convs
    dw3x3_kernel<<<12544, 256, 0, stream>>>(S0, wavw,        wavs,       nullptr, nullptr, T0, 128, 28, 28);
    dw3x3_kernel<<<3136,  256, 0, stream>>>(S1, wavw + 1152, wavs + 128, nullptr, nullptr, T1, 128, 14, 14);
    dw3x3_kernel<<<784,   256, 0, stream>>>(S2, wavw + 2304, wavs + 256, nullptr, nullptr, T2, 128, 7, 7);
    dw3x3_kernel<<<256,   256, 0, stream>>>(S3, wavw + 3456, wavs + 384, nullptr, nullptr, T3, 128, 4, 4);
    dw3x3_kernel<<<64,    256, 0, stream>>>(S4, wavw + 4608, wavs + 512, nullptr, nullptr, T4, 128, 2, 2);

    // 4. IDWT cascade
    idwt_kernel<<<64,    256, 0, stream>>>(T4, nullptr, RA, 2, 2, 4, 4);
    idwt_kernel<<<196,   256, 0, stream>>>(T3, RA, RB, 4, 4, 7, 7);
    idwt_kernel<<<784,   256, 0, stream>>>(T2, RB, RA, 7, 7, 14, 14);
    idwt_kernel<<<3136,  256, 0, stream>>>(T1, RA, RB, 14, 14, 28, 28);
    idwt_kernel<<<12544, 256, 0, stream>>>(T0, RB, RA, 28, 28, 56, 56);

    // 5. base depthwise conv -> bf16 NHWC
    dwbase_kernel<<<12544, 256, 0, stream>>>(XCI, wbw, wbs, wbb, RA, CIMGb);

    // 6. cp2d implicit-GEMM MFMA
    cp2d_mfma_kernel<<<dim3(49, 32), 256, 0, stream>>>(CIMGb, cpwt, cpb, CBUF);

    // 7. cn -> ACATb[96:128]
    cn_kernel<<<392, 256, 0, stream>>>(CBUF, cnw, cnb, ACATb);

    // 8/9. spatial reductions
    sr_kernel<<<588,  256, 0, stream>>>(XA, sr1w, sr1b, X1P, 8, 7);
    sr_kernel<<<2352, 256, 0, stream>>>(XA, sr2w, sr2b, X2P, 4, 14);

    // 10. LN96 + gelu -> bf16
    ln96_kernel<<<392,  256, 0, stream>>>(X1P, an1w, an1b, X1Bb, 1568);
    ln96_kernel<<<1568, 256, 0, stream>>>(X2P, an2w, an2b, X2Bb, 6272);

    // 11. q / kv GEMMs (q -> head-major)
    gemm_kernel<6,false,false,2><<<dim3(1, 1568), 256, 0, stream>>>(XAb,  qwt,   nullptr, nullptr, QB,  100352, 96, 96);
    gemm_kernel<6,false,false,0><<<dim3(1, 25),   256, 0, stream>>>(X1Bb, kv1wt, nullptr, nullptr, KV1, 1568,   96, 96);
    gemm_kernel<6,false,false,0><<<dim3(1, 98),   256, 0, stream>>>(X2Bb, kv2wt, nullptr, nullptr, KV2, 6272,   96, 96);

    // 12. merged attention -> ACATb[0:96]
    attn_kernel<<<dim3(13, 8, 32), 256, 0, stream>>>(QB, KV1, KV2, ACATb);

    // 13. proj + bias + residual(x) -> XRES
    gemm_kernel<4,false,true,0><<<dim3(2, 1568), 256, 0, stream>>>(ACATb, pwt, pb, x, XRES, 100352, 128, 128);

    // 14. LN2 -> bf16
    ln2_kernel<<<25088, 256, 0, stream>>>(XRES, ln2w, ln2b, XNb);

    // 15. fc1 + bias + gelu -> Hb bf16
    gemm_kernel<4,true,false,1><<<dim3(8, 1568), 256, 0, stream>>>(XNb, w1t, f1b, nullptr, Hb, 100352, 128, 512);

    // 16. fc2 + bias + residual(XRES) -> d_out fp32
    gemm_kernel<4,false,true,0><<<dim3(2, 1568), 256, 0, stream>>>(Hb, w2t, f2b, XRES, dout, 100352, 512, 128);
}